// Round 10
// baseline (1086.746 us; speedup 1.0000x reference)
//
#include <hip/hip_runtime.h>
#include <hip/hip_bf16.h>
#include <cstdint>

// Problem constants (EnBaseLayer: E(n)-GNN layer)
#define NN 50000
#define NE 600000
#define HD 128
#define NG 20
#define EF 4
#define K1 280            // 2H + NG + EF
#define TILES (NE/64)     // 9375
#define EGRID 512         // 2 blocks/CU resident
#define ROWU 148          // s_inp row stride in u32 (592 B = 37*16)
#define NTILE 782         // ceil(NN/64)
#define SW(r) ((r) ^ (((r)>>3)&7))   // LDS 16B-slot swizzle within 8-row group
#define EDW 12            // edata u32 words per edge

typedef __attribute__((ext_vector_type(4))) float f32x4;
typedef __attribute__((ext_vector_type(8))) __bf16 bf16x8;
typedef __attribute__((ext_vector_type(4))) unsigned int u32x4;

__device__ __forceinline__ float fast_rcp(float x){ return __builtin_amdgcn_rcpf(x); }
__device__ __forceinline__ float silu_f(float x){ return x * fast_rcp(1.0f + __expf(-x)); }
__device__ __forceinline__ float sigmoid_f(float x){ return fast_rcp(1.0f + __expf(-x)); }
__device__ __forceinline__ float tanh_f(float x){ return 1.0f - 2.0f*fast_rcp(__expf(2.0f*x)+1.0f); }

__device__ __forceinline__ uint32_t pk2(float a, float b){   // RNE f32x2 -> bf16x2
  uint32_t ua = __float_as_uint(a); ua += 0x7FFFu + ((ua>>16)&1u);
  uint32_t ub = __float_as_uint(b); ub += 0x7FFFu + ((ub>>16)&1u);
  return (ua>>16) | (ub & 0xFFFF0000u);
}
__device__ __forceinline__ uint16_t bfb(float a){
  uint32_t ua = __float_as_uint(a); ua += 0x7FFFu + ((ua>>16)&1u);
  return (uint16_t)(ua>>16);
}
__device__ __forceinline__ float bf2f(uint16_t b){ return __uint_as_float(((uint32_t)b)<<16); }
__device__ __forceinline__ f32x4 MF(u32x4 a, u32x4 b, f32x4 c){
  return __builtin_amdgcn_mfma_f32_16x16x32_bf16(
      __builtin_bit_cast(bf16x8, a), __builtin_bit_cast(bf16x8, b), c, 0, 0, 0);
}

// ---------------------------------------------------------------------------
// Pre-kernels: h->bf16, CSR build (hist -> scan -> fill), edge pregather
// ---------------------------------------------------------------------------
__global__ void __launch_bounds__(256) h2bf_kernel(
    const float* __restrict__ h, uint32_t* __restrict__ hb)
{
  const size_t i = ((size_t)blockIdx.x*256 + threadIdx.x)*8;
  const float4 a = *reinterpret_cast<const float4*>(h + i);
  const float4 b = *reinterpret_cast<const float4*>(h + i + 4);
  u32x4 v = {pk2(a.x,a.y), pk2(a.z,a.w), pk2(b.x,b.y), pk2(b.z,b.w)};
  *reinterpret_cast<u32x4*>(hb + i/2) = v;
}

__global__ void __launch_bounds__(512) hist_kernel(
    const int* __restrict__ ei, int* __restrict__ cnt)
{
  const int e = blockIdx.x*512 + threadIdx.x;
  if (e < NE) atomicAdd(&cnt[ei[NE + e]], 1);
}

__global__ void __launch_bounds__(512) scanA_kernel(
    int* __restrict__ cur, int* __restrict__ bsums)
{
  __shared__ int s[512];
  const int tid = threadIdx.x;
  const int i = blockIdx.x*512 + tid;
  const int v = (i < NN) ? cur[i] : 0;
  s[tid] = v; __syncthreads();
  #pragma unroll
  for (int d = 1; d < 512; d <<= 1){
    const int t = (tid >= d) ? s[tid-d] : 0;
    __syncthreads();
    s[tid] += t;
    __syncthreads();
  }
  if (i < NN) cur[i] = s[tid] - v;             // exclusive within block
  if (tid == 511) bsums[blockIdx.x] = s[511];  // block total
}

__global__ void scanB_kernel(int* __restrict__ bsums)
{
  if (threadIdx.x == 0 && blockIdx.x == 0){
    int acc = 0;
    for (int b = 0; b < 98; ++b){ const int t = bsums[b]; bsums[b] = acc; acc += t; }
  }
}

__global__ void __launch_bounds__(512) scanC_kernel(
    int* __restrict__ cur, const int* __restrict__ bsums)
{
  const int i = blockIdx.x*512 + threadIdx.x;
  if (i < NN) cur[i] += bsums[blockIdx.x];
}

__global__ void __launch_bounds__(512) fill_kernel(
    const int* __restrict__ ei, int* __restrict__ cur, int* __restrict__ perm)
{
  const int e = blockIdx.x*512 + threadIdx.x;
  if (e < NE){
    const int p = atomicAdd(&cur[ei[NE + e]], 1);
    perm[p] = e;
  }
}

// pregather: materialize per-edge data in perm (dst-sorted) order
// edata[i] = { src, dst, relx, rely, relz, dist, ea0, ea1, ea2, ea3, -, - }
__global__ void __launch_bounds__(256) pregather_kernel(
    const int* __restrict__ ei, const float* __restrict__ x,
    const float* __restrict__ eattr, const int* __restrict__ perm,
    uint32_t* __restrict__ edata)
{
  const int i = blockIdx.x*256 + threadIdx.x;
  if (i >= NE) return;
  const int e = perm[i];
  const int sj = ei[e], dj = ei[NE + e];
  const float ax = x[dj*3+0]-x[sj*3+0];
  const float ay = x[dj*3+1]-x[sj*3+1];
  const float az = x[dj*3+2]-x[sj*3+2];
  const float dd = sqrtf(ax*ax + ay*ay + az*az + 1e-8f);
  const float4 e4 = *reinterpret_cast<const float4*>(eattr + (size_t)e*EF);
  uint32_t* dp = edata + (size_t)i*EDW;
  u32x4 v0 = {(uint32_t)sj, (uint32_t)dj, __float_as_uint(ax), __float_as_uint(ay)};
  u32x4 v1 = {__float_as_uint(az), __float_as_uint(dd), __float_as_uint(e4.x), __float_as_uint(e4.y)};
  u32x4 v2 = {__float_as_uint(e4.z), __float_as_uint(e4.w), 0u, 0u};
  *reinterpret_cast<u32x4*>(dp)     = v0;
  *reinterpret_cast<u32x4*>(dp + 4) = v1;
  *reinterpret_cast<u32x4*>(dp + 8) = v2;
}

// ---------------------------------------------------------------------------
// Edge kernel: R6 structure (5 barriers, per-edge atomics hidden under GEMM3)
// with dst-sorted edata + bf16 hb inputs. Sorted dsts give the per-edge
// atomics L2 line locality (each out line RMW'd by one block/XCD), cutting
// atomic HBM traffic ~10x with zero structural serialization.
// 8 waves/block, tile = 64 edges; wave w owns cols 16w..16w+15.
// A-frag: lane l holds row l&15, k = 32ks + 8*(l>>4) + j.
// D-frag: row(m)=4*(l>>4)+reg, col(n)=l&15.
// ---------------------------------------------------------------------------
#define EDGE_LDS_U32 (64*ROWU + 4096 + 4096 + 448)
#define EDGE_LDS_B (EDGE_LDS_U32*4)   // 72448 B -> 2 blocks/CU

__global__ void __launch_bounds__(512, 4) edge_srt_kernel(
    const uint32_t* __restrict__ hb, const uint32_t* __restrict__ edata,
    const float* __restrict__ We1, const float* __restrict__ be1,
    const float* __restrict__ We2, const float* __restrict__ be2,
    const float* __restrict__ Winf, const float* __restrict__ binf,
    const float* __restrict__ Wx1, const float* __restrict__ bx1,
    const float* __restrict__ Wx2, float* __restrict__ out)
{
  extern __shared__ uint32_t smem[];
  uint32_t* s_inp = smem;                                   // [64][ROWU]
  uint16_t* t1f   = (uint16_t*)(smem + 64*ROWU);            // [16][64][8] u16
  uint16_t* mf_   = (uint16_t*)(smem + 64*ROWU + 4096);     // [16][64][8] u16
  uint32_t* tl    = smem + 64*ROWU + 8192;
  int*   s_dst  = (int*)tl;            // 64
  float* s_rel  = (float*)(tl+64);     // 192
  float* s_dist = (float*)(tl+256);    // 64
  float* s_pe   = (float*)(tl+320);    // 64
  float* s_pg   = (float*)(tl+384);    // 64

  const int tid = threadIdx.x;
  const int w = tid >> 6, l = tid & 63;
  const int lo = l & 15, hi = l >> 4;
  const int col = w*16 + lo;
  const int r8 = tid >> 3, p8 = tid & 7;
  const int ks2 = w >> 1;
  const int lp  = ((w&1)*2 + (lo>>3))*16 + 4*hi;
  const int jj  = lo & 7;
  const int lsw = SW(l);

  // ---- persistent weight B-fragments (17 frags = 68 regs) ----
  u32x4 B1[9], B2[4], B3[4];
  #pragma unroll
  for (int ks = 0; ks < 9; ++ks){
    float f[8];
    #pragma unroll
    for (int j = 0; j < 8; ++j){
      const int k = ks*32 + hi*8 + j;
      f[j] = (k < K1) ? We1[k*HD + col] : 0.0f;
    }
    B1[ks] = {pk2(f[0],f[1]), pk2(f[2],f[3]), pk2(f[4],f[5]), pk2(f[6],f[7])};
  }
  #pragma unroll
  for (int ks = 0; ks < 4; ++ks){
    float f2[8], f3[8];
    #pragma unroll
    for (int j = 0; j < 8; ++j){
      const int k = ks*32 + hi*8 + j;
      f2[j] = We2[k*HD + col];
      f3[j] = Wx1[k*HD + col];
    }
    B2[ks] = {pk2(f2[0],f2[1]), pk2(f2[2],f2[3]), pk2(f2[4],f2[5]), pk2(f2[6],f2[7])};
    B3[ks] = {pk2(f3[0],f3[1]), pk2(f3[2],f3[3]), pk2(f3[4],f3[5]), pk2(f3[6],f3[7])};
  }
  const float vbe1 = be1[col], vbe2 = be2[col], vbx1 = bx1[col];
  const float wi = Winf[col], wx = Wx2[col], vbinf = binf[0];
  const float SP = 10.0f/19.0f;
  const float CO = -0.5f/(SP*SP);

  for (int t = blockIdx.x; t < TILES; t += EGRID){
    const int ebase = t*64;
    __syncthreads();                         // prior tile fully consumed

    // ---- phase A (tid<64): sequential edata read, geometry, gauss cols ----
    if (tid < 64){
      const uint32_t* ed = edata + (size_t)(ebase + tid)*EDW;
      const u32x4 w0 = *reinterpret_cast<const u32x4*>(ed);
      const u32x4 w1 = *reinterpret_cast<const u32x4*>(ed + 4);
      const u32x4 w2 = *reinterpret_cast<const u32x4*>(ed + 8);
      const int dj   = (int)w0.y;
      const float ax = __uint_as_float(w0.z);
      const float ay = __uint_as_float(w0.w);
      const float az = __uint_as_float(w1.x);
      const float dd = __uint_as_float(w1.y);
      s_dst[tid] = dj;
      s_rel[3*tid+0]=ax; s_rel[3*tid+1]=ay; s_rel[3*tid+2]=az;
      s_dist[tid]=dd; s_pe[tid]=0.0f; s_pg[tid]=0.0f;
      float g[24];
      #pragma unroll
      for (int j = 0; j < 20; ++j){ const float a = dd - j*SP; g[j] = __expf(CO*a*a); }
      g[20]=__uint_as_float(w1.z); g[21]=__uint_as_float(w1.w);
      g[22]=__uint_as_float(w2.x); g[23]=__uint_as_float(w2.y);
      uint32_t* gp = s_inp + tid*ROWU + 128;
      u32x4 g0v = {pk2(g[0],g[1]),  pk2(g[2],g[3]),  pk2(g[4],g[5]),  pk2(g[6],g[7])};
      u32x4 g1v = {pk2(g[8],g[9]),  pk2(g[10],g[11]),pk2(g[12],g[13]),pk2(g[14],g[15])};
      u32x4 g2v = {pk2(g[16],g[17]),pk2(g[18],g[19]),pk2(g[20],g[21]),pk2(g[22],g[23])};
      u32x4 g3v = {0,0,0,0};
      *reinterpret_cast<u32x4*>(gp)    = g0v;
      *reinterpret_cast<u32x4*>(gp+4)  = g1v;
      *reinterpret_cast<u32x4*>(gp+8)  = g2v;
      *reinterpret_cast<u32x4*>(gp+12) = g3v;
    }
    // ---- phase B: gather bf16 h rows (dst sorted -> L1/L2 run reuse) ----
    {
      const uint32_t node = edata[(size_t)(ebase + r8)*EDW + (p8 < 4 ? 1 : 0)];
      const uint32_t* hw = hb + (size_t)node*(HD/2) + (p8&3)*16;
      uint32_t* dp = s_inp + r8*ROWU + p8*16;
      #pragma unroll
      for (int q = 0; q < 4; ++q)
        *reinterpret_cast<u32x4*>(dp + 4*q) = *reinterpret_cast<const u32x4*>(hw + 4*q);
    }
    __syncthreads();                         // tile staged

    // ---------------- GEMM1: t1 = silu(inp @ We1 + be1) ----------------
    #pragma unroll
    for (int Mt = 0; Mt < 4; ++Mt){
      const uint32_t* arow = s_inp + (Mt*16 + lo)*ROWU + hi*4;
      f32x4 acc = {0,0,0,0};
      #pragma unroll
      for (int ks = 0; ks < 9; ++ks)
        acc = MF(*reinterpret_cast<const u32x4*>(arow + ks*16), B1[ks], acc);
      #pragma unroll
      for (int reg = 0; reg < 4; ++reg)
        t1f[((Mt*4 + ks2)*64 + SW(lp+reg))*8 + jj] = bfb(silu_f(acc[reg] + vbe1));
    }
    __syncthreads();                         // t1f ready

    // ---------------- GEMM2: mij = silu(t1 @ We2 + be2); eij partials ----
    #pragma unroll
    for (int Mt = 0; Mt < 4; ++Mt){
      f32x4 acc = {0,0,0,0};
      #pragma unroll
      for (int ks = 0; ks < 4; ++ks)
        acc = MF(*reinterpret_cast<const u32x4*>(t1f + ((Mt*4+ks)*64 + lsw)*8), B2[ks], acc);
      float p[4];
      #pragma unroll
      for (int reg = 0; reg < 4; ++reg){
        const float m = silu_f(acc[reg] + vbe2);
        mf_[((Mt*4 + ks2)*64 + SW(lp+reg))*8 + jj] = bfb(m);
        p[reg] = m * wi;
      }
      #pragma unroll
      for (int msk = 1; msk < 16; msk <<= 1){
        #pragma unroll
        for (int reg = 0; reg < 4; ++reg) p[reg] += __shfl_xor(p[reg], msk);
      }
      if (lo == 0){
        #pragma unroll
        for (int reg = 0; reg < 4; ++reg) atomicAdd(&s_pe[Mt*16 + 4*hi + reg], p[reg]);
      }
    }
    __syncthreads();                         // mf_ + s_pe ready

    // ---- mi scatter: per-edge atomics, sorted dst -> XCD-local lines ----
    #pragma unroll
    for (int Mt = 0; Mt < 4; ++Mt){
      #pragma unroll
      for (int reg = 0; reg < 4; ++reg){
        const int r = Mt*16 + 4*hi + reg;
        const float eij = sigmoid_f(s_pe[r] + vbinf);
        const float m = bf2f(mf_[((Mt*4 + ks2)*64 + SW(lp+reg))*8 + jj]);
        atomicAdd(out + (size_t)s_dst[r]*HD + col, m*eij);
      }
    }
    // ---------------- GEMM3: gate partials (hides atomic latency) --------
    #pragma unroll
    for (int Mt = 0; Mt < 4; ++Mt){
      f32x4 acc = {0,0,0,0};
      #pragma unroll
      for (int ks = 0; ks < 4; ++ks)
        acc = MF(*reinterpret_cast<const u32x4*>(mf_ + ((Mt*4+ks)*64 + lsw)*8), B3[ks], acc);
      float p[4];
      #pragma unroll
      for (int reg = 0; reg < 4; ++reg)
        p[reg] = silu_f(acc[reg] + vbx1) * wx;
      #pragma unroll
      for (int msk = 1; msk < 16; msk <<= 1){
        #pragma unroll
        for (int reg = 0; reg < 4; ++reg) p[reg] += __shfl_xor(p[reg], msk);
      }
      if (lo == 0){
        #pragma unroll
        for (int reg = 0; reg < 4; ++reg) atomicAdd(&s_pg[Mt*16 + 4*hi + reg], p[reg]);
      }
    }
    __syncthreads();                         // s_pg ready

    // ---------------- dx scatter ----------------
    if (tid < 192){
      const int er = tid/3, c = tid - 3*er;
      const float gate = tanh_f(s_pg[er]);
      const float sc = gate * fast_rcp(s_dist[er] + 1.0f);
      atomicAdd(out + (size_t)NN*HD + (size_t)s_dst[er]*3 + c, s_rel[3*er+c]*sc);
    }
  }
}

// ---------------------------------------------------------------------------
// Fallback edge kernel (round 6, f32-h, unsorted per-edge atomics).
// ---------------------------------------------------------------------------
__global__ void __launch_bounds__(512, 4) edge_fb_kernel(
    const float* __restrict__ h, const float* __restrict__ x,
    const int* __restrict__ ei, const float* __restrict__ eattr,
    const float* __restrict__ We1, const float* __restrict__ be1,
    const float* __restrict__ We2, const float* __restrict__ be2,
    const float* __restrict__ Winf, const float* __restrict__ binf,
    const float* __restrict__ Wx1, const float* __restrict__ bx1,
    const float* __restrict__ Wx2, float* __restrict__ out)
{
  extern __shared__ uint32_t smem[];
  uint32_t* s_inp = smem;
  uint16_t* t1f   = (uint16_t*)(smem + 64*ROWU);
  uint16_t* mf_   = (uint16_t*)(smem + 64*ROWU + 4096);
  uint32_t* tl    = smem + 64*ROWU + 8192;
  int*   s_dst  = (int*)tl;
  float* s_rel  = (float*)(tl+64);
  float* s_dist = (float*)(tl+256);
  float* s_pe   = (float*)(tl+320);
  float* s_pg   = (float*)(tl+384);

  const int tid = threadIdx.x;
  const int w = tid >> 6, l = tid & 63;
  const int lo = l & 15, hi = l >> 4;
  const int col = w*16 + lo;
  const int r8 = tid >> 3, p8 = tid & 7;
  const int ks2 = w >> 1;
  const int lp  = ((w&1)*2 + (lo>>3))*16 + 4*hi;
  const int jj  = lo & 7;
  const int lsw = SW(l);

  u32x4 B1[9], B2[4], B3[4];
  #pragma unroll
  for (int ks = 0; ks < 9; ++ks){
    float f[8];
    #pragma unroll
    for (int j = 0; j < 8; ++j){
      const int k = ks*32 + hi*8 + j;
      f[j] = (k < K1) ? We1[k*HD + col] : 0.0f;
    }
    B1[ks] = {pk2(f[0],f[1]), pk2(f[2],f[3]), pk2(f[4],f[5]), pk2(f[6],f[7])};
  }
  #pragma unroll
  for (int ks = 0; ks < 4; ++ks){
    float f2[8], f3[8];
    #pragma unroll
    for (int j = 0; j < 8; ++j){
      const int k = ks*32 + hi*8 + j;
      f2[j] = We2[k*HD + col];
      f3[j] = Wx1[k*HD + col];
    }
    B2[ks] = {pk2(f2[0],f2[1]), pk2(f2[2],f2[3]), pk2(f2[4],f2[5]), pk2(f2[6],f2[7])};
    B3[ks] = {pk2(f3[0],f3[1]), pk2(f3[2],f3[3]), pk2(f3[4],f3[5]), pk2(f3[6],f3[7])};
  }
  const float vbe1 = be1[col], vbe2 = be2[col], vbx1 = bx1[col];
  const float wi = Winf[col], wx = Wx2[col], vbinf = binf[0];
  const float SP = 10.0f/19.0f;
  const float CO = -0.5f/(SP*SP);

  for (int t = blockIdx.x; t < TILES; t += EGRID){
    const int ebase = t*64;
    __syncthreads();
    if (tid < 64){
      const int sj = ei[ebase+tid], dj = ei[NE+ebase+tid];
      const float ax = x[dj*3+0]-x[sj*3+0];
      const float ay = x[dj*3+1]-x[sj*3+1];
      const float az = x[dj*3+2]-x[sj*3+2];
      const float dd = sqrtf(ax*ax + ay*ay + az*az + 1e-8f);
      s_dst[tid] = dj;
      s_rel[3*tid+0]=ax; s_rel[3*tid+1]=ay; s_rel[3*tid+2]=az;
      s_dist[tid]=dd; s_pe[tid]=0.0f; s_pg[tid]=0.0f;
      float g[24];
      #pragma unroll
      for (int j = 0; j < 20; ++j){ const float a = dd - j*SP; g[j] = __expf(CO*a*a); }
      const float4 e4 = *reinterpret_cast<const float4*>(eattr + (size_t)(ebase+tid)*EF);
      g[20]=e4.x; g[21]=e4.y; g[22]=e4.z; g[23]=e4.w;
      uint32_t* gp = s_inp + tid*ROWU + 128;
      u32x4 g0v = {pk2(g[0],g[1]),  pk2(g[2],g[3]),  pk2(g[4],g[5]),  pk2(g[6],g[7])};
      u32x4 g1v = {pk2(g[8],g[9]),  pk2(g[10],g[11]),pk2(g[12],g[13]),pk2(g[14],g[15])};
      u32x4 g2v = {pk2(g[16],g[17]),pk2(g[18],g[19]),pk2(g[20],g[21]),pk2(g[22],g[23])};
      u32x4 g3v = {0,0,0,0};
      *reinterpret_cast<u32x4*>(gp)    = g0v;
      *reinterpret_cast<u32x4*>(gp+4)  = g1v;
      *reinterpret_cast<u32x4*>(gp+8)  = g2v;
      *reinterpret_cast<u32x4*>(gp+12) = g3v;
    }
    {
      const int e = ebase + r8;
      const int node = (p8 < 4) ? ei[NE + e] : ei[e];
      const float* hp = h + (size_t)node*HD + (p8&3)*32;
      uint32_t* dp = s_inp + r8*ROWU + p8*16;
      #pragma unroll
      for (int q = 0; q < 4; ++q){
        const float4 va = *reinterpret_cast<const float4*>(hp + 8*q);
        const float4 vb = *reinterpret_cast<const float4*>(hp + 8*q + 4);
        u32x4 v = { pk2(va.x,va.y), pk2(va.z,va.w), pk2(vb.x,vb.y), pk2(vb.z,vb.w) };
        *reinterpret_cast<u32x4*>(dp + 4*q) = v;
      }
    }
    __syncthreads();

    #pragma unroll
    for (int Mt = 0; Mt < 4; ++Mt){
      const uint32_t* arow = s_inp + (Mt*16 + lo)*ROWU + hi*4;
      f32x4 acc = {0,0,0,0};
      #pragma unroll
      for (int ks = 0; ks < 9; ++ks)
        acc = MF(*reinterpret_cast<const u32x4*>(arow + ks*16), B1[ks], acc);
      #pragma unroll
      for (int reg = 0; reg < 4; ++reg)
        t1f[((Mt*4 + ks2)*64 + SW(lp+reg))*8 + jj] = bfb(silu_f(acc[reg] + vbe1));
    }
    __syncthreads();

    #pragma unroll
    for (int Mt = 0; Mt < 4; ++Mt){
      f32x4 acc = {0,0,0,0};
      #pragma unroll
      for (int ks = 0; ks < 4; ++ks)
        acc = MF(*reinterpret_cast<const u32x4*>(t1f + ((Mt*4+ks)*64 + lsw)*8), B2[ks], acc);
      float p[4];
      #pragma unroll
      for (int reg = 0; reg < 4; ++reg){
        const float m = silu_f(acc[reg] + vbe2);
        mf_[((Mt*4 + ks2)*64 + SW(lp+reg))*8 + jj] = bfb(m);
        p[reg] = m * wi;
      }
      #pragma unroll
      for (int msk = 1; msk < 16; msk <<= 1){
        #pragma unroll
        for (int reg = 0; reg < 4; ++reg) p[reg] += __shfl_xor(p[reg], msk);
      }
      if (lo == 0){
        #pragma unroll
        for (int reg = 0; reg < 4; ++reg) atomicAdd(&s_pe[Mt*16 + 4*hi + reg], p[reg]);
      }
    }
    __syncthreads();

    #pragma unroll
    for (int Mt = 0; Mt < 4; ++Mt){
      #pragma unroll
      for (int reg = 0; reg < 4; ++reg){
        const int r = Mt*16 + 4*hi + reg;
        const float eij = sigmoid_f(s_pe[r] + vbinf);
        const float m = bf2f(mf_[((Mt*4 + ks2)*64 + SW(lp+reg))*8 + jj]);
        atomicAdd(out + (size_t)s_dst[r]*HD + col, m*eij);
      }
    }
    #pragma unroll
    for (int Mt = 0; Mt < 4; ++Mt){
      f32x4 acc = {0,0,0,0};
      #pragma unroll
      for (int ks = 0; ks < 4; ++ks)
        acc = MF(*reinterpret_cast<const u32x4*>(mf_ + ((Mt*4+ks)*64 + lsw)*8), B3[ks], acc);
      float p[4];
      #pragma unroll
      for (int reg = 0; reg < 4; ++reg)
        p[reg] = silu_f(acc[reg] + vbx1) * wx;
      #pragma unroll
      for (int msk = 1; msk < 16; msk <<= 1){
        #pragma unroll
        for (int reg = 0; reg < 4; ++reg) p[reg] += __shfl_xor(p[reg], msk);
      }
      if (lo == 0){
        #pragma unroll
        for (int reg = 0; reg < 4; ++reg) atomicAdd(&s_pg[Mt*16 + 4*hi + reg], p[reg]);
      }
    }
    __syncthreads();

    if (tid < 192){
      const int er = tid/3, c = tid - 3*er;
      const float gate = tanh_f(s_pg[er]);
      const float sc = gate * fast_rcp(s_dist[er] + 1.0f);
      atomicAdd(out + (size_t)NN*HD + (size_t)s_dst[er]*3 + c, s_rel[3*er+c]*sc);
    }
  }
}

// ---------------------------------------------------------------------------
// Node kernel (MFMA), unchanged.
// ---------------------------------------------------------------------------
#define CROW 132

__global__ void __launch_bounds__(512, 4) node_kernel(
    const float* __restrict__ h, const float* __restrict__ x,
    const float* __restrict__ mask,
    const float* __restrict__ Wn1, const float* __restrict__ bn1,
    const float* __restrict__ Wn2, const float* __restrict__ bn2,
    float* __restrict__ out)
{
  __shared__ uint32_t s_cat[64*CROW];
  __shared__ __align__(16) uint16_t t1n[4*4*64*8];

  const int tid = threadIdx.x;
  const int w = tid >> 6, l = tid & 63;
  const int lo = l & 15, hi = l >> 4;
  const int col = w*16 + lo;

  u32x4 Bn1[8], Bn2[4];
  #pragma unroll
  for (int ks = 0; ks < 8; ++ks){
    float f[8];
    #pragma unroll
    for (int j = 0; j < 8; ++j) f[j] = Wn1[(ks*32 + hi*8 + j)*HD + col];
    Bn1[ks] = {pk2(f[0],f[1]), pk2(f[2],f[3]), pk2(f[4],f[5]), pk2(f[6],f[7])};
  }
  #pragma unroll
  for (int ks = 0; ks < 4; ++ks){
    float f[8];
    #pragma unroll
    for (int j = 0; j < 8; ++j) f[j] = Wn2[(ks*32 + hi*8 + j)*HD + col];
    Bn2[ks] = {pk2(f[0],f[1]), pk2(f[2],f[3]), pk2(f[4],f[5]), pk2(f[6],f[7])};
  }
  const float vbn1 = bn1[col], vbn2 = bn2[col];
  const int nbase = blockIdx.x*64;
  const int ks2 = w >> 1;
  const int lp  = ((w&1)*2 + (lo>>3))*16 + 4*hi;
  const int jj  = lo & 7;

  {
    const int r = tid >> 3, p = tid & 7;
    const int n = nbase + r;
    uint32_t* dp = s_cat + r*CROW + p*16;
    if (n < NN){
      const float* sp = (p < 4) ? (out + (size_t)n*HD + p*32)
                                : (h   + (size_t)n*HD + (p-4)*32);
      #pragma unroll
      for (int q = 0; q < 8; ++q){
        const float4 v = *reinterpret_cast<const float4*>(sp + 4*q);
        dp[2*q]   = pk2(v.x, v.y);
        dp[2*q+1] = pk2(v.z, v.w);
      }
    } else {
      #pragma unroll
      for (int q = 0; q < 16; ++q) dp[q] = 0u;
    }
  }
  __syncthreads();

  #pragma unroll
  for (int Mt = 0; Mt < 4; ++Mt){
    const uint32_t* arow = s_cat + (Mt*16 + lo)*CROW + hi*4;
    f32x4 acc = {0,0,0,0};
    #pragma unroll
    for (int ks = 0; ks < 8; ++ks)
      acc = MF(*reinterpret_cast<const u32x4*>(arow + ks*16), Bn1[ks], acc);
    uint16_t* tp = t1n + ((Mt*4 + ks2)*64 + lp)*8 + jj;
    #pragma unroll
    for (int reg = 0; reg < 4; ++reg)
      tp[reg*8] = bfb(silu_f(acc[reg] + vbn1));
  }
  __syncthreads();

  #pragma unroll
  for (int Mt = 0; Mt < 4; ++Mt){
    f32x4 acc = {0,0,0,0};
    #pragma unroll
    for (int ks = 0; ks < 4; ++ks)
      acc = MF(*reinterpret_cast<const u32x4*>(t1n + ((Mt*4+ks)*64 + l)*8), Bn2[ks], acc);
    #pragma unroll
    for (int reg = 0; reg < 4; ++reg){
      const int n = nbase + Mt*16 + 4*hi + reg;
      if (n < NN)
        out[(size_t)n*HD + col] = h[(size_t)n*HD + col] + acc[reg] + vbn2;
    }
  }

  if (tid < 192){
    const int r = tid/3, c = tid - 3*r;
    const int n = nbase + r;
    if (n < NN){
      const size_t ix = (size_t)NN*HD + (size_t)n*3 + c;
      out[ix] = x[(size_t)n*3 + c] + out[ix]*mask[n];
    }
  }
}

extern "C" void kernel_launch(void* const* d_in, const int* in_sizes, int n_in,
                              void* d_out, int out_size, void* d_ws, size_t ws_size,
                              hipStream_t stream) {
  (void)in_sizes; (void)n_in;
  const float* h    = (const float*)d_in[0];
  const float* x    = (const float*)d_in[1];
  const int*   ei   = (const int*)  d_in[2];
  const float* mask = (const float*)d_in[3];
  const float* ea   = (const float*)d_in[4];
  const float* We1  = (const float*)d_in[5];
  const float* be1  = (const float*)d_in[6];
  const float* We2  = (const float*)d_in[7];
  const float* be2  = (const float*)d_in[8];
  const float* Winf = (const float*)d_in[9];
  const float* binf = (const float*)d_in[10];
  const float* Wx1  = (const float*)d_in[11];
  const float* bx1  = (const float*)d_in[12];
  const float* Wx2  = (const float*)d_in[13];
  const float* Wn1  = (const float*)d_in[14];
  const float* bn1  = (const float*)d_in[15];
  const float* Wn2  = (const float*)d_in[16];
  const float* bn2  = (const float*)d_in[17];
  float* out = (float*)d_out;

  // ws layout (u32): hb[3.2M] | cursor[50k] | perm[600k] | bsums[128] | edata[7.2M]
  uint32_t* hb    = (uint32_t*)d_ws;
  int* cursor     = (int*)d_ws + 3200000;
  int* perm       = (int*)d_ws + 3250000;
  int* bsums      = (int*)d_ws + 3850000;
  uint32_t* edata = (uint32_t*)d_ws + 3850128;
  const size_t need = (size_t)(3850128 + (size_t)NE*EDW) * 4;   // ~44.2 MB
  const bool use_srt = ws_size >= need;

  hipFuncSetAttribute(reinterpret_cast<const void*>(edge_srt_kernel),
                      hipFuncAttributeMaxDynamicSharedMemorySize, EDGE_LDS_B);
  hipFuncSetAttribute(reinterpret_cast<const void*>(edge_fb_kernel),
                      hipFuncAttributeMaxDynamicSharedMemorySize, EDGE_LDS_B);

  // out[0..NN*HD) accumulates mi; out[NN*HD..) accumulates delta_x
  hipMemsetAsync(d_out, 0, (size_t)out_size * sizeof(float), stream);

  if (use_srt){
    hipMemsetAsync(cursor, 0, (size_t)NN*4, stream);
    h2bf_kernel<<<3125, 256, 0, stream>>>(h, hb);
    hist_kernel<<<1172, 512, 0, stream>>>(ei, cursor);
    scanA_kernel<<<98, 512, 0, stream>>>(cursor, bsums);
    scanB_kernel<<<1, 64, 0, stream>>>(bsums);
    scanC_kernel<<<98, 512, 0, stream>>>(cursor, bsums);
    fill_kernel<<<1172, 512, 0, stream>>>(ei, cursor, perm);
    pregather_kernel<<<2344, 256, 0, stream>>>(ei, x, ea, perm, edata);
    edge_srt_kernel<<<EGRID, 512, EDGE_LDS_B, stream>>>(
        hb, edata, We1, be1, We2, be2, Winf, binf, Wx1, bx1, Wx2, out);
  } else {
    edge_fb_kernel<<<EGRID, 512, EDGE_LDS_B, stream>>>(
        h, x, ei, ea, We1, be1, We2, be2, Winf, binf, Wx1, bx1, Wx2, out);
  }
  node_kernel<<<NTILE, 512, 0, stream>>>(
      h, x, mask, Wn1, bn1, Wn2, bn2, out);
}

// Round 11
// 487.935 us; speedup vs baseline: 2.2272x; 2.2272x over previous
//
#include <hip/hip_runtime.h>
#include <hip/hip_bf16.h>
#include <cstdint>

// Problem constants (EnBaseLayer: E(n)-GNN layer)
#define NN 50000
#define NE 600000
#define HD 128
#define NG 20
#define EF 4
#define K1 280            // 2H + NG + EF
#define TILES (NE/64)     // 9375
#define EGRID 512         // 2 blocks/CU resident
#define ROWU 148          // s_inp row stride in u32 (592 B = 37*16)
#define NTILE 782         // ceil(NN/64)
#define SW(r) ((r) ^ (((r)>>3)&7))   // LDS 16B-slot swizzle within 8-row group
#define EDW 12            // edata u32 words per edge

typedef __attribute__((ext_vector_type(4))) float f32x4;
typedef __attribute__((ext_vector_type(8))) __bf16 bf16x8;
typedef __attribute__((ext_vector_type(4))) unsigned int u32x4;

__device__ __forceinline__ float fast_rcp(float x){ return __builtin_amdgcn_rcpf(x); }
__device__ __forceinline__ float silu_f(float x){ return x * fast_rcp(1.0f + __expf(-x)); }
__device__ __forceinline__ float sigmoid_f(float x){ return fast_rcp(1.0f + __expf(-x)); }
__device__ __forceinline__ float tanh_f(float x){ return 1.0f - 2.0f*fast_rcp(__expf(2.0f*x)+1.0f); }

__device__ __forceinline__ uint32_t pk2(float a, float b){   // RNE f32x2 -> bf16x2
  uint32_t ua = __float_as_uint(a); ua += 0x7FFFu + ((ua>>16)&1u);
  uint32_t ub = __float_as_uint(b); ub += 0x7FFFu + ((ub>>16)&1u);
  return (ua>>16) | (ub & 0xFFFF0000u);
}
__device__ __forceinline__ uint16_t bfb(float a){
  uint32_t ua = __float_as_uint(a); ua += 0x7FFFu + ((ua>>16)&1u);
  return (uint16_t)(ua>>16);
}
__device__ __forceinline__ float bf2f(uint16_t b){ return __uint_as_float(((uint32_t)b)<<16); }
__device__ __forceinline__ f32x4 MF(u32x4 a, u32x4 b, f32x4 c){
  return __builtin_amdgcn_mfma_f32_16x16x32_bf16(
      __builtin_bit_cast(bf16x8, a), __builtin_bit_cast(bf16x8, b), c, 0, 0, 0);
}
// inverse of the mf_ fragment write index: value (row r, col c)
__device__ __forceinline__ int mf_idx(int r, int c){
  return (((r>>4)*4 + (c>>5))*64 + SW(((((c>>4)&1)<<1) + ((c>>3)&1))*16 + (r&15)))*8 + (c&7);
}

// ---------------------------------------------------------------------------
// Pre-kernels: h->bf16, CSR build (hist -> scan -> fill), edge pregather
// ---------------------------------------------------------------------------
__global__ void __launch_bounds__(256) h2bf_kernel(
    const float* __restrict__ h, uint32_t* __restrict__ hb)
{
  const size_t i = ((size_t)blockIdx.x*256 + threadIdx.x)*8;
  const float4 a = *reinterpret_cast<const float4*>(h + i);
  const float4 b = *reinterpret_cast<const float4*>(h + i + 4);
  u32x4 v = {pk2(a.x,a.y), pk2(a.z,a.w), pk2(b.x,b.y), pk2(b.z,b.w)};
  *reinterpret_cast<u32x4*>(hb + i/2) = v;
}

__global__ void __launch_bounds__(512) hist_kernel(
    const int* __restrict__ ei, int* __restrict__ cnt)
{
  const int e = blockIdx.x*512 + threadIdx.x;
  if (e < NE) atomicAdd(&cnt[ei[NE + e]], 1);
}

__global__ void __launch_bounds__(512) scanA_kernel(
    int* __restrict__ cur, int* __restrict__ bsums)
{
  __shared__ int s[512];
  const int tid = threadIdx.x;
  const int i = blockIdx.x*512 + tid;
  const int v = (i < NN) ? cur[i] : 0;
  s[tid] = v; __syncthreads();
  #pragma unroll
  for (int d = 1; d < 512; d <<= 1){
    const int t = (tid >= d) ? s[tid-d] : 0;
    __syncthreads();
    s[tid] += t;
    __syncthreads();
  }
  if (i < NN) cur[i] = s[tid] - v;             // exclusive within block
  if (tid == 511) bsums[blockIdx.x] = s[511];  // block total
}

__global__ void scanB_kernel(int* __restrict__ bsums)
{
  if (threadIdx.x == 0 && blockIdx.x == 0){
    int acc = 0;
    for (int b = 0; b < 98; ++b){ const int t = bsums[b]; bsums[b] = acc; acc += t; }
  }
}

__global__ void __launch_bounds__(512) scanC_kernel(
    int* __restrict__ cur, const int* __restrict__ bsums)
{
  const int i = blockIdx.x*512 + threadIdx.x;
  if (i < NN) cur[i] += bsums[blockIdx.x];
}

__global__ void __launch_bounds__(512) fill_kernel(
    const int* __restrict__ ei, int* __restrict__ cur, int* __restrict__ perm)
{
  const int e = blockIdx.x*512 + threadIdx.x;
  if (e < NE){
    const int p = atomicAdd(&cur[ei[NE + e]], 1);
    perm[p] = e;
  }
}

// pregather: materialize per-edge data in perm (dst-sorted) order
// edata[i] = { src, dst, relx, rely, relz, dist, ea0, ea1, ea2, ea3, -, - }
__global__ void __launch_bounds__(256) pregather_kernel(
    const int* __restrict__ ei, const float* __restrict__ x,
    const float* __restrict__ eattr, const int* __restrict__ perm,
    uint32_t* __restrict__ edata)
{
  const int i = blockIdx.x*256 + threadIdx.x;
  if (i >= NE) return;
  const int e = perm[i];
  const int sj = ei[e], dj = ei[NE + e];
  const float ax = x[dj*3+0]-x[sj*3+0];
  const float ay = x[dj*3+1]-x[sj*3+1];
  const float az = x[dj*3+2]-x[sj*3+2];
  const float dd = sqrtf(ax*ax + ay*ay + az*az + 1e-8f);
  const float4 e4 = *reinterpret_cast<const float4*>(eattr + (size_t)e*EF);
  uint32_t* dp = edata + (size_t)i*EDW;
  u32x4 v0 = {(uint32_t)sj, (uint32_t)dj, __float_as_uint(ax), __float_as_uint(ay)};
  u32x4 v1 = {__float_as_uint(az), __float_as_uint(dd), __float_as_uint(e4.x), __float_as_uint(e4.y)};
  u32x4 v2 = {__float_as_uint(e4.z), __float_as_uint(e4.w), 0u, 0u};
  *reinterpret_cast<u32x4*>(dp)     = v0;
  *reinterpret_cast<u32x4*>(dp + 4) = v1;
  *reinterpret_cast<u32x4*>(dp + 8) = v2;
}

// ---------------------------------------------------------------------------
// Edge kernel: R6/R10 barrier skeleton + run-reduced, contention-free scatter.
// dst-sorted tiles; ballot-derived run table (s_ustart/s_udst, U runs/tile).
// mi scatter: each (run u, col c) output owned by exactly ONE thread ->
//   one atomic per output, no same-address collisions, hidden under GEMM3.
// dx scatter: same, U*3 outputs.
// 8 waves/block, tile = 64 edges; wave w owns cols 16w..16w+15.
// A-frag: lane l holds row l&15, k = 32ks + 8*(l>>4) + j.
// D-frag: row(m)=4*(l>>4)+reg, col(n)=l&15.
// ---------------------------------------------------------------------------
#define EDGE_LDS_U32 (64*ROWU + 4096 + 4096 + 704)
#define EDGE_LDS_B (EDGE_LDS_U32*4)   // 73472 B -> 2 blocks/CU

__global__ void __launch_bounds__(512, 4) edge_red_kernel(
    const uint32_t* __restrict__ hb, const uint32_t* __restrict__ edata,
    const float* __restrict__ We1, const float* __restrict__ be1,
    const float* __restrict__ We2, const float* __restrict__ be2,
    const float* __restrict__ Winf, const float* __restrict__ binf,
    const float* __restrict__ Wx1, const float* __restrict__ bx1,
    const float* __restrict__ Wx2, float* __restrict__ out)
{
  extern __shared__ uint32_t smem[];
  uint32_t* s_inp = smem;                                   // [64][ROWU]
  uint16_t* t1f   = (uint16_t*)(smem + 64*ROWU);            // [16][64][8] u16
  uint16_t* mf_   = (uint16_t*)(smem + 64*ROWU + 4096);     // [16][64][8] u16
  uint32_t* tl    = smem + 64*ROWU + 8192;
  int*   s_dst    = (int*)tl;            // 64
  float* s_rel    = (float*)(tl+64);     // 192
  float* s_dist   = (float*)(tl+256);    // 64
  float* s_pe     = (float*)(tl+320);    // 64
  float* s_pg     = (float*)(tl+384);    // 64
  int*   s_udst   = (int*)(tl+448);      // 64
  int*   s_ustart = (int*)(tl+512);      // 65
  int*   s_Un     = (int*)(tl+580);      // 1

  const int tid = threadIdx.x;
  const int w = tid >> 6, l = tid & 63;
  const int lo = l & 15, hi = l >> 4;
  const int col = w*16 + lo;
  const int r8 = tid >> 3, p8 = tid & 7;
  const int ks2 = w >> 1;
  const int lp  = ((w&1)*2 + (lo>>3))*16 + 4*hi;
  const int jj  = lo & 7;
  const int lsw = SW(l);

  // ---- persistent weight B-fragments (17 frags = 68 regs) ----
  u32x4 B1[9], B2[4], B3[4];
  #pragma unroll
  for (int ks = 0; ks < 9; ++ks){
    float f[8];
    #pragma unroll
    for (int j = 0; j < 8; ++j){
      const int k = ks*32 + hi*8 + j;
      f[j] = (k < K1) ? We1[k*HD + col] : 0.0f;
    }
    B1[ks] = {pk2(f[0],f[1]), pk2(f[2],f[3]), pk2(f[4],f[5]), pk2(f[6],f[7])};
  }
  #pragma unroll
  for (int ks = 0; ks < 4; ++ks){
    float f2[8], f3[8];
    #pragma unroll
    for (int j = 0; j < 8; ++j){
      const int k = ks*32 + hi*8 + j;
      f2[j] = We2[k*HD + col];
      f3[j] = Wx1[k*HD + col];
    }
    B2[ks] = {pk2(f2[0],f2[1]), pk2(f2[2],f2[3]), pk2(f2[4],f2[5]), pk2(f2[6],f2[7])};
    B3[ks] = {pk2(f3[0],f3[1]), pk2(f3[2],f3[3]), pk2(f3[4],f3[5]), pk2(f3[6],f3[7])};
  }
  const float vbe1 = be1[col], vbe2 = be2[col], vbx1 = bx1[col];
  const float wi = Winf[col], wx = Wx2[col], vbinf = binf[0];
  const float SP = 10.0f/19.0f;
  const float CO = -0.5f/(SP*SP);

  for (int t = blockIdx.x; t < TILES; t += EGRID){
    const int ebase = t*64;
    __syncthreads();                         // prior tile fully consumed

    // ---- phase A (tid<64): sequential edata read, run table, gauss cols ----
    if (tid < 64){
      const uint32_t* ed = edata + (size_t)(ebase + tid)*EDW;
      const u32x4 w0 = *reinterpret_cast<const u32x4*>(ed);
      const u32x4 w1 = *reinterpret_cast<const u32x4*>(ed + 4);
      const u32x4 w2 = *reinterpret_cast<const u32x4*>(ed + 8);
      const int dj   = (int)w0.y;
      const float ax = __uint_as_float(w0.z);
      const float ay = __uint_as_float(w0.w);
      const float az = __uint_as_float(w1.x);
      const float dd = __uint_as_float(w1.y);
      s_dst[tid] = dj;
      s_rel[3*tid+0]=ax; s_rel[3*tid+1]=ay; s_rel[3*tid+2]=az;
      s_dist[tid]=dd; s_pe[tid]=0.0f; s_pg[tid]=0.0f;
      // run table over sorted dst (wave-ballot run detection)
      const int dprev = __shfl_up(dj, 1);
      const int isnew = (tid == 0) || (dj != dprev);
      const unsigned long long mball = __ballot(isnew);
      const int slot = __popcll(mball << (63 - tid)) - 1;
      if (isnew){ s_udst[slot] = dj; s_ustart[slot] = tid; }
      if (tid == 63){ s_Un[0] = slot + 1; s_ustart[slot + 1] = 64; }
      // gauss smearing + edge_attr columns
      float g[24];
      #pragma unroll
      for (int j = 0; j < 20; ++j){ const float a = dd - j*SP; g[j] = __expf(CO*a*a); }
      g[20]=__uint_as_float(w1.z); g[21]=__uint_as_float(w1.w);
      g[22]=__uint_as_float(w2.x); g[23]=__uint_as_float(w2.y);
      uint32_t* gp = s_inp + tid*ROWU + 128;
      u32x4 g0v = {pk2(g[0],g[1]),  pk2(g[2],g[3]),  pk2(g[4],g[5]),  pk2(g[6],g[7])};
      u32x4 g1v = {pk2(g[8],g[9]),  pk2(g[10],g[11]),pk2(g[12],g[13]),pk2(g[14],g[15])};
      u32x4 g2v = {pk2(g[16],g[17]),pk2(g[18],g[19]),pk2(g[20],g[21]),pk2(g[22],g[23])};
      u32x4 g3v = {0,0,0,0};
      *reinterpret_cast<u32x4*>(gp)    = g0v;
      *reinterpret_cast<u32x4*>(gp+4)  = g1v;
      *reinterpret_cast<u32x4*>(gp+8)  = g2v;
      *reinterpret_cast<u32x4*>(gp+12) = g3v;
    }
    // ---- phase B: gather bf16 h rows (dst sorted -> L1/L2 run reuse) ----
    {
      const uint32_t node = edata[(size_t)(ebase + r8)*EDW + (p8 < 4 ? 1 : 0)];
      const uint32_t* hw = hb + (size_t)node*(HD/2) + (p8&3)*16;
      uint32_t* dp = s_inp + r8*ROWU + p8*16;
      #pragma unroll
      for (int q = 0; q < 4; ++q)
        *reinterpret_cast<u32x4*>(dp + 4*q) = *reinterpret_cast<const u32x4*>(hw + 4*q);
    }
    __syncthreads();                         // tile staged

    // ---------------- GEMM1: t1 = silu(inp @ We1 + be1) ----------------
    #pragma unroll
    for (int Mt = 0; Mt < 4; ++Mt){
      const uint32_t* arow = s_inp + (Mt*16 + lo)*ROWU + hi*4;
      f32x4 acc = {0,0,0,0};
      #pragma unroll
      for (int ks = 0; ks < 9; ++ks)
        acc = MF(*reinterpret_cast<const u32x4*>(arow + ks*16), B1[ks], acc);
      #pragma unroll
      for (int reg = 0; reg < 4; ++reg)
        t1f[((Mt*4 + ks2)*64 + SW(lp+reg))*8 + jj] = bfb(silu_f(acc[reg] + vbe1));
    }
    __syncthreads();                         // t1f ready

    // ---------------- GEMM2: mij = silu(t1 @ We2 + be2); eij partials ----
    #pragma unroll
    for (int Mt = 0; Mt < 4; ++Mt){
      f32x4 acc = {0,0,0,0};
      #pragma unroll
      for (int ks = 0; ks < 4; ++ks)
        acc = MF(*reinterpret_cast<const u32x4*>(t1f + ((Mt*4+ks)*64 + lsw)*8), B2[ks], acc);
      float p[4];
      #pragma unroll
      for (int reg = 0; reg < 4; ++reg){
        const float m = silu_f(acc[reg] + vbe2);
        mf_[((Mt*4 + ks2)*64 + SW(lp+reg))*8 + jj] = bfb(m);
        p[reg] = m * wi;
      }
      #pragma unroll
      for (int msk = 1; msk < 16; msk <<= 1){
        #pragma unroll
        for (int reg = 0; reg < 4; ++reg) p[reg] += __shfl_xor(p[reg], msk);
      }
      if (lo == 0){
        #pragma unroll
        for (int reg = 0; reg < 4; ++reg) atomicAdd(&s_pe[Mt*16 + 4*hi + reg], p[reg]);
      }
    }
    __syncthreads();                         // mf_ + s_pe + run table ready

    // ---- mi run-reduced scatter: one thread per (run u, col c) output ----
    const int U = s_Un[0];
    for (int idx = tid; idx < U*HD; idx += 512){
      const int u = idx >> 7, c = idx & 127;
      const int r1 = s_ustart[u+1];
      float acc = 0.0f;
      for (int r = s_ustart[u]; r < r1; ++r){
        const float eij = sigmoid_f(s_pe[r] + vbinf);
        acc += bf2f(mf_[mf_idx(r, c)]) * eij;
      }
      atomicAdd(out + (size_t)s_udst[u]*HD + c, acc);
    }
    // ---------------- GEMM3: gate partials (hides atomic latency) --------
    #pragma unroll
    for (int Mt = 0; Mt < 4; ++Mt){
      f32x4 acc = {0,0,0,0};
      #pragma unroll
      for (int ks = 0; ks < 4; ++ks)
        acc = MF(*reinterpret_cast<const u32x4*>(mf_ + ((Mt*4+ks)*64 + lsw)*8), B3[ks], acc);
      float p[4];
      #pragma unroll
      for (int reg = 0; reg < 4; ++reg)
        p[reg] = silu_f(acc[reg] + vbx1) * wx;
      #pragma unroll
      for (int msk = 1; msk < 16; msk <<= 1){
        #pragma unroll
        for (int reg = 0; reg < 4; ++reg) p[reg] += __shfl_xor(p[reg], msk);
      }
      if (lo == 0){
        #pragma unroll
        for (int reg = 0; reg < 4; ++reg) atomicAdd(&s_pg[Mt*16 + 4*hi + reg], p[reg]);
      }
    }
    __syncthreads();                         // s_pg ready

    // ---- dx run-reduced scatter: one thread per (run u, comp) output ----
    for (int idx = tid; idx < U*3; idx += 512){
      const int u = idx/3, cc = idx - 3*u;
      const int r1 = s_ustart[u+1];
      float acc = 0.0f;
      for (int r = s_ustart[u]; r < r1; ++r){
        const float gate = tanh_f(s_pg[r]);
        acc += s_rel[3*r+cc] * gate * fast_rcp(s_dist[r] + 1.0f);
      }
      atomicAdd(out + (size_t)NN*HD + (size_t)s_udst[u]*3 + cc, acc);
    }
  }
}

// ---------------------------------------------------------------------------
// Fallback edge kernel (round 6, f32-h, unsorted per-edge atomics).
// ---------------------------------------------------------------------------
#define FB_LDS_U32 (64*ROWU + 4096 + 4096 + 448)
#define FB_LDS_B (FB_LDS_U32*4)

__global__ void __launch_bounds__(512, 4) edge_fb_kernel(
    const float* __restrict__ h, const float* __restrict__ x,
    const int* __restrict__ ei, const float* __restrict__ eattr,
    const float* __restrict__ We1, const float* __restrict__ be1,
    const float* __restrict__ We2, const float* __restrict__ be2,
    const float* __restrict__ Winf, const float* __restrict__ binf,
    const float* __restrict__ Wx1, const float* __restrict__ bx1,
    const float* __restrict__ Wx2, float* __restrict__ out)
{
  extern __shared__ uint32_t smem[];
  uint32_t* s_inp = smem;
  uint16_t* t1f   = (uint16_t*)(smem + 64*ROWU);
  uint16_t* mf_   = (uint16_t*)(smem + 64*ROWU + 4096);
  uint32_t* tl    = smem + 64*ROWU + 8192;
  int*   s_dst  = (int*)tl;
  float* s_rel  = (float*)(tl+64);
  float* s_dist = (float*)(tl+256);
  float* s_pe   = (float*)(tl+320);
  float* s_pg   = (float*)(tl+384);

  const int tid = threadIdx.x;
  const int w = tid >> 6, l = tid & 63;
  const int lo = l & 15, hi = l >> 4;
  const int col = w*16 + lo;
  const int r8 = tid >> 3, p8 = tid & 7;
  const int ks2 = w >> 1;
  const int lp  = ((w&1)*2 + (lo>>3))*16 + 4*hi;
  const int jj  = lo & 7;
  const int lsw = SW(l);

  u32x4 B1[9], B2[4], B3[4];
  #pragma unroll
  for (int ks = 0; ks < 9; ++ks){
    float f[8];
    #pragma unroll
    for (int j = 0; j < 8; ++j){
      const int k = ks*32 + hi*8 + j;
      f[j] = (k < K1) ? We1[k*HD + col] : 0.0f;
    }
    B1[ks] = {pk2(f[0],f[1]), pk2(f[2],f[3]), pk2(f[4],f[5]), pk2(f[6],f[7])};
  }
  #pragma unroll
  for (int ks = 0; ks < 4; ++ks){
    float f2[8], f3[8];
    #pragma unroll
    for (int j = 0; j < 8; ++j){
      const int k = ks*32 + hi*8 + j;
      f2[j] = We2[k*HD + col];
      f3[j] = Wx1[k*HD + col];
    }
    B2[ks] = {pk2(f2[0],f2[1]), pk2(f2[2],f2[3]), pk2(f2[4],f2[5]), pk2(f2[6],f2[7])};
    B3[ks] = {pk2(f3[0],f3[1]), pk2(f3[2],f3[3]), pk2(f3[4],f3[5]), pk2(f3[6],f3[7])};
  }
  const float vbe1 = be1[col], vbe2 = be2[col], vbx1 = bx1[col];
  const float wi = Winf[col], wx = Wx2[col], vbinf = binf[0];
  const float SP = 10.0f/19.0f;
  const float CO = -0.5f/(SP*SP);

  for (int t = blockIdx.x; t < TILES; t += EGRID){
    const int ebase = t*64;
    __syncthreads();
    if (tid < 64){
      const int sj = ei[ebase+tid], dj = ei[NE+ebase+tid];
      const float ax = x[dj*3+0]-x[sj*3+0];
      const float ay = x[dj*3+1]-x[sj*3+1];
      const float az = x[dj*3+2]-x[sj*3+2];
      const float dd = sqrtf(ax*ax + ay*ay + az*az + 1e-8f);
      s_dst[tid] = dj;
      s_rel[3*tid+0]=ax; s_rel[3*tid+1]=ay; s_rel[3*tid+2]=az;
      s_dist[tid]=dd; s_pe[tid]=0.0f; s_pg[tid]=0.0f;
      float g[24];
      #pragma unroll
      for (int j = 0; j < 20; ++j){ const float a = dd - j*SP; g[j] = __expf(CO*a*a); }
      const float4 e4 = *reinterpret_cast<const float4*>(eattr + (size_t)(ebase+tid)*EF);
      g[20]=e4.x; g[21]=e4.y; g[22]=e4.z; g[23]=e4.w;
      uint32_t* gp = s_inp + tid*ROWU + 128;
      u32x4 g0v = {pk2(g[0],g[1]),  pk2(g[2],g[3]),  pk2(g[4],g[5]),  pk2(g[6],g[7])};
      u32x4 g1v = {pk2(g[8],g[9]),  pk2(g[10],g[11]),pk2(g[12],g[13]),pk2(g[14],g[15])};
      u32x4 g2v = {pk2(g[16],g[17]),pk2(g[18],g[19]),pk2(g[20],g[21]),pk2(g[22],g[23])};
      u32x4 g3v = {0,0,0,0};
      *reinterpret_cast<u32x4*>(gp)    = g0v;
      *reinterpret_cast<u32x4*>(gp+4)  = g1v;
      *reinterpret_cast<u32x4*>(gp+8)  = g2v;
      *reinterpret_cast<u32x4*>(gp+12) = g3v;
    }
    {
      const int e = ebase + r8;
      const int node = (p8 < 4) ? ei[NE + e] : ei[e];
      const float* hp = h + (size_t)node*HD + (p8&3)*32;
      uint32_t* dp = s_inp + r8*ROWU + p8*16;
      #pragma unroll
      for (int q = 0; q < 4; ++q){
        const float4 va = *reinterpret_cast<const float4*>(hp + 8*q);
        const float4 vb = *reinterpret_cast<const float4*>(hp + 8*q + 4);
        u32x4 v = { pk2(va.x,va.y), pk2(va.z,va.w), pk2(vb.x,vb.y), pk2(vb.z,vb.w) };
        *reinterpret_cast<u32x4*>(dp + 4*q) = v;
      }
    }
    __syncthreads();

    #pragma unroll
    for (int Mt = 0; Mt < 4; ++Mt){
      const uint32_t* arow = s_inp + (Mt*16 + lo)*ROWU + hi*4;
      f32x4 acc = {0,0,0,0};
      #pragma unroll
      for (int ks = 0; ks < 9; ++ks)
        acc = MF(*reinterpret_cast<const u32x4*>(arow + ks*16), B1[ks], acc);
      #pragma unroll
      for (int reg = 0; reg < 4; ++reg)
        t1f[((Mt*4 + ks2)*64 + SW(lp+reg))*8 + jj] = bfb(silu_f(acc[reg] + vbe1));
    }
    __syncthreads();

    #pragma unroll
    for (int Mt = 0; Mt < 4; ++Mt){
      f32x4 acc = {0,0,0,0};
      #pragma unroll
      for (int ks = 0; ks < 4; ++ks)
        acc = MF(*reinterpret_cast<const u32x4*>(t1f + ((Mt*4+ks)*64 + lsw)*8), B2[ks], acc);
      float p[4];
      #pragma unroll
      for (int reg = 0; reg < 4; ++reg){
        const float m = silu_f(acc[reg] + vbe2);
        mf_[((Mt*4 + ks2)*64 + SW(lp+reg))*8 + jj] = bfb(m);
        p[reg] = m * wi;
      }
      #pragma unroll
      for (int msk = 1; msk < 16; msk <<= 1){
        #pragma unroll
        for (int reg = 0; reg < 4; ++reg) p[reg] += __shfl_xor(p[reg], msk);
      }
      if (lo == 0){
        #pragma unroll
        for (int reg = 0; reg < 4; ++reg) atomicAdd(&s_pe[Mt*16 + 4*hi + reg], p[reg]);
      }
    }
    __syncthreads();

    #pragma unroll
    for (int Mt = 0; Mt < 4; ++Mt){
      #pragma unroll
      for (int reg = 0; reg < 4; ++reg){
        const int r = Mt*16 + 4*hi + reg;
        const float eij = sigmoid_f(s_pe[r] + vbinf);
        const float m = bf2f(mf_[((Mt*4 + ks2)*64 + SW(lp+reg))*8 + jj]);
        atomicAdd(out + (size_t)s_dst[r]*HD + col, m*eij);
      }
    }
    #pragma unroll
    for (int Mt = 0; Mt < 4; ++Mt){
      f32x4 acc = {0,0,0,0};
      #pragma unroll
      for (int ks = 0; ks < 4; ++ks)
        acc = MF(*reinterpret_cast<const u32x4*>(mf_ + ((Mt*4+ks)*64 + lsw)*8), B3[ks], acc);
      float p[4];
      #pragma unroll
      for (int reg = 0; reg < 4; ++reg)
        p[reg] = silu_f(acc[reg] + vbx1) * wx;
      #pragma unroll
      for (int msk = 1; msk < 16; msk <<= 1){
        #pragma unroll
        for (int reg = 0; reg < 4; ++reg) p[reg] += __shfl_xor(p[reg], msk);
      }
      if (lo == 0){
        #pragma unroll
        for (int reg = 0; reg < 4; ++reg) atomicAdd(&s_pg[Mt*16 + 4*hi + reg], p[reg]);
      }
    }
    __syncthreads();

    if (tid < 192){
      const int er = tid/3, c = tid - 3*er;
      const float gate = tanh_f(s_pg[er]);
      const float sc = gate * fast_rcp(s_dist[er] + 1.0f);
      atomicAdd(out + (size_t)NN*HD + (size_t)s_dst[er]*3 + c, s_rel[3*er+c]*sc);
    }
  }
}

// ---------------------------------------------------------------------------
// Node kernel (MFMA), unchanged.
// ---------------------------------------------------------------------------
#define CROW 132

__global__ void __launch_bounds__(512, 4) node_kernel(
    const float* __restrict__ h, const float* __restrict__ x,
    const float* __restrict__ mask,
    const float* __restrict__ Wn1, const float* __restrict__ bn1,
    const float* __restrict__ Wn2, const float* __restrict__ bn2,
    float* __restrict__ out)
{
  __shared__ uint32_t s_cat[64*CROW];
  __shared__ __align__(16) uint16_t t1n[4*4*64*8];

  const int tid = threadIdx.x;
  const int w = tid >> 6, l = tid & 63;
  const int lo = l & 15, hi = l >> 4;
  const int col = w*16 + lo;

  u32x4 Bn1[8], Bn2[4];
  #pragma unroll
  for (int ks = 0; ks < 8; ++ks){
    float f[8];
    #pragma unroll
    for (int j = 0; j < 8; ++j) f[j] = Wn1[(ks*32 + hi*8 + j)*HD + col];
    Bn1[ks] = {pk2(f[0],f[1]), pk2(f[2],f[3]), pk2(f[4],f[5]), pk2(f[6],f[7])};
  }
  #pragma unroll
  for (int ks = 0; ks < 4; ++ks){
    float f[8];
    #pragma unroll
    for (int j = 0; j < 8; ++j) f[j] = Wn2[(ks*32 + hi*8 + j)*HD + col];
    Bn2[ks] = {pk2(f[0],f[1]), pk2(f[2],f[3]), pk2(f[4],f[5]), pk2(f[6],f[7])};
  }
  const float vbn1 = bn1[col], vbn2 = bn2[col];
  const int nbase = blockIdx.x*64;
  const int ks2 = w >> 1;
  const int lp  = ((w&1)*2 + (lo>>3))*16 + 4*hi;
  const int jj  = lo & 7;

  {
    const int r = tid >> 3, p = tid & 7;
    const int n = nbase + r;
    uint32_t* dp = s_cat + r*CROW + p*16;
    if (n < NN){
      const float* sp = (p < 4) ? (out + (size_t)n*HD + p*32)
                                : (h   + (size_t)n*HD + (p-4)*32);
      #pragma unroll
      for (int q = 0; q < 8; ++q){
        const float4 v = *reinterpret_cast<const float4*>(sp + 4*q);
        dp[2*q]   = pk2(v.x, v.y);
        dp[2*q+1] = pk2(v.z, v.w);
      }
    } else {
      #pragma unroll
      for (int q = 0; q < 16; ++q) dp[q] = 0u;
    }
  }
  __syncthreads();

  #pragma unroll
  for (int Mt = 0; Mt < 4; ++Mt){
    const uint32_t* arow = s_cat + (Mt*16 + lo)*CROW + hi*4;
    f32x4 acc = {0,0,0,0};
    #pragma unroll
    for (int ks = 0; ks < 8; ++ks)
      acc = MF(*reinterpret_cast<const u32x4*>(arow + ks*16), Bn1[ks], acc);
    uint16_t* tp = t1n + ((Mt*4 + ks2)*64 + lp)*8 + jj;
    #pragma unroll
    for (int reg = 0; reg < 4; ++reg)
      tp[reg*8] = bfb(silu_f(acc[reg] + vbn1));
  }
  __syncthreads();

  #pragma unroll
  for (int Mt = 0; Mt < 4; ++Mt){
    f32x4 acc = {0,0,0,0};
    #pragma unroll
    for (int ks = 0; ks < 4; ++ks)
      acc = MF(*reinterpret_cast<const u32x4*>(t1n + ((Mt*4+ks)*64 + l)*8), Bn2[ks], acc);
    #pragma unroll
    for (int reg = 0; reg < 4; ++reg){
      const int n = nbase + Mt*16 + 4*hi + reg;
      if (n < NN)
        out[(size_t)n*HD + col] = h[(size_t)n*HD + col] + acc[reg] + vbn2;
    }
  }

  if (tid < 192){
    const int r = tid/3, c = tid - 3*r;
    const int n = nbase + r;
    if (n < NN){
      const size_t ix = (size_t)NN*HD + (size_t)n*3 + c;
      out[ix] = x[(size_t)n*3 + c] + out[ix]*mask[n];
    }
  }
}

extern "C" void kernel_launch(void* const* d_in, const int* in_sizes, int n_in,
                              void* d_out, int out_size, void* d_ws, size_t ws_size,
                              hipStream_t stream) {
  (void)in_sizes; (void)n_in;
  const float* h    = (const float*)d_in[0];
  const float* x    = (const float*)d_in[1];
  const int*   ei   = (const int*)  d_in[2];
  const float* mask = (const float*)d_in[3];
  const float* ea   = (const float*)d_in[4];
  const float* We1  = (const float*)d_in[5];
  const float* be1  = (const float*)d_in[6];
  const float* We2  = (const float*)d_in[7];
  const float* be2  = (const float*)d_in[8];
  const float* Winf = (const float*)d_in[9];
  const float* binf = (const float*)d_in[10];
  const float* Wx1  = (const float*)d_in[11];
  const float* bx1  = (const float*)d_in[12];
  const float* Wx2  = (const float*)d_in[13];
  const float* Wn1  = (const float*)d_in[14];
  const float* bn1  = (const float*)d_in[15];
  const float* Wn2  = (const float*)d_in[16];
  const float* bn2  = (const float*)d_in[17];
  float* out = (float*)d_out;

  // ws layout (u32): hb[3.2M] | cursor[50k] | perm[600k] | bsums[128] | edata[7.2M]
  uint32_t* hb    = (uint32_t*)d_ws;
  int* cursor     = (int*)d_ws + 3200000;
  int* perm       = (int*)d_ws + 3250000;
  int* bsums      = (int*)d_ws + 3850000;
  uint32_t* edata = (uint32_t*)d_ws + 3850128;
  const size_t need = (size_t)(3850128 + (size_t)NE*EDW) * 4;   // ~44.2 MB
  const bool use_red = ws_size >= need;

  hipFuncSetAttribute(reinterpret_cast<const void*>(edge_red_kernel),
                      hipFuncAttributeMaxDynamicSharedMemorySize, EDGE_LDS_B);
  hipFuncSetAttribute(reinterpret_cast<const void*>(edge_fb_kernel),
                      hipFuncAttributeMaxDynamicSharedMemorySize, FB_LDS_B);

  // out[0..NN*HD) accumulates mi; out[NN*HD..) accumulates delta_x
  hipMemsetAsync(d_out, 0, (size_t)out_size * sizeof(float), stream);

  if (use_red){
    hipMemsetAsync(cursor, 0, (size_t)NN*4, stream);
    h2bf_kernel<<<3125, 256, 0, stream>>>(h, hb);
    hist_kernel<<<1172, 512, 0, stream>>>(ei, cursor);
    scanA_kernel<<<98, 512, 0, stream>>>(cursor, bsums);
    scanB_kernel<<<1, 64, 0, stream>>>(bsums);
    scanC_kernel<<<98, 512, 0, stream>>>(cursor, bsums);
    fill_kernel<<<1172, 512, 0, stream>>>(ei, cursor, perm);
    pregather_kernel<<<2344, 256, 0, stream>>>(ei, x, ea, perm, edata);
    edge_red_kernel<<<EGRID, 512, EDGE_LDS_B, stream>>>(
        hb, edata, We1, be1, We2, be2, Winf, binf, Wx1, bx1, Wx2, out);
  } else {
    edge_fb_kernel<<<EGRID, 512, FB_LDS_B, stream>>>(
        h, x, ei, ea, We1, be1, We2, be2, Winf, binf, Wx1, bx1, Wx2, out);
  }
  node_kernel<<<NTILE, 512, 0, stream>>>(
      h, x, mask, Wn1, bn1, Wn2, bn2, out);
}

// Round 12
// 454.254 us; speedup vs baseline: 2.3924x; 1.0741x over previous
//
#include <hip/hip_runtime.h>
#include <hip/hip_bf16.h>
#include <cstdint>

// Problem constants (EnBaseLayer: E(n)-GNN layer)
#define NN 50000
#define NE 600000
#define HD 128
#define NG 20
#define EF 4
#define K1 280            // 2H + NG + EF
#define TILES (NE/64)     // 9375
#define EGRID 512         // 2 blocks/CU resident
#define ROWU 148          // s_inp row stride in u32 (592 B = 37*16)
#define NTILE 782         // ceil(NN/64)
#define SW(r) ((r) ^ (((r)>>3)&7))   // LDS 16B-slot swizzle within 8-row group
#define EDW 12            // edata u32 words per edge
#define TLW 520           // per-tile tl block size in u32 (ping-pong)

typedef __attribute__((ext_vector_type(4))) float f32x4;
typedef __attribute__((ext_vector_type(8))) __bf16 bf16x8;
typedef __attribute__((ext_vector_type(4))) unsigned int u32x4;

__device__ __forceinline__ float fast_rcp(float x){ return __builtin_amdgcn_rcpf(x); }
__device__ __forceinline__ float silu_f(float x){ return x * fast_rcp(1.0f + __expf(-x)); }
__device__ __forceinline__ float sigmoid_f(float x){ return fast_rcp(1.0f + __expf(-x)); }
__device__ __forceinline__ float tanh_f(float x){ return 1.0f - 2.0f*fast_rcp(__expf(2.0f*x)+1.0f); }

__device__ __forceinline__ uint32_t pk2(float a, float b){   // RNE f32x2 -> bf16x2
  uint32_t ua = __float_as_uint(a); ua += 0x7FFFu + ((ua>>16)&1u);
  uint32_t ub = __float_as_uint(b); ub += 0x7FFFu + ((ub>>16)&1u);
  return (ua>>16) | (ub & 0xFFFF0000u);
}
__device__ __forceinline__ uint16_t bfb(float a){
  uint32_t ua = __float_as_uint(a); ua += 0x7FFFu + ((ua>>16)&1u);
  return (uint16_t)(ua>>16);
}
__device__ __forceinline__ float bf2f(uint16_t b){ return __uint_as_float(((uint32_t)b)<<16); }
__device__ __forceinline__ f32x4 MF(u32x4 a, u32x4 b, f32x4 c){
  return __builtin_amdgcn_mfma_f32_16x16x32_bf16(
      __builtin_bit_cast(bf16x8, a), __builtin_bit_cast(bf16x8, b), c, 0, 0, 0);
}

// ---------------------------------------------------------------------------
// Pre-kernels: h->bf16, CSR build (hist -> scan -> fill), edge pregather
// ---------------------------------------------------------------------------
__global__ void __launch_bounds__(256) h2bf_kernel(
    const float* __restrict__ h, uint32_t* __restrict__ hb)
{
  const size_t i = ((size_t)blockIdx.x*256 + threadIdx.x)*8;
  const float4 a = *reinterpret_cast<const float4*>(h + i);
  const float4 b = *reinterpret_cast<const float4*>(h + i + 4);
  u32x4 v = {pk2(a.x,a.y), pk2(a.z,a.w), pk2(b.x,b.y), pk2(b.z,b.w)};
  *reinterpret_cast<u32x4*>(hb + i/2) = v;
}

__global__ void __launch_bounds__(512) hist_kernel(
    const int* __restrict__ ei, int* __restrict__ cnt)
{
  const int e = blockIdx.x*512 + threadIdx.x;
  if (e < NE) atomicAdd(&cnt[ei[NE + e]], 1);
}

__global__ void __launch_bounds__(512) scanA_kernel(
    int* __restrict__ cur, int* __restrict__ bsums)
{
  __shared__ int s[512];
  const int tid = threadIdx.x;
  const int i = blockIdx.x*512 + tid;
  const int v = (i < NN) ? cur[i] : 0;
  s[tid] = v; __syncthreads();
  #pragma unroll
  for (int d = 1; d < 512; d <<= 1){
    const int t = (tid >= d) ? s[tid-d] : 0;
    __syncthreads();
    s[tid] += t;
    __syncthreads();
  }
  if (i < NN) cur[i] = s[tid] - v;             // exclusive within block
  if (tid == 511) bsums[blockIdx.x] = s[511];  // block total
}

__global__ void scanB_kernel(int* __restrict__ bsums)
{
  if (threadIdx.x == 0 && blockIdx.x == 0){
    int acc = 0;
    for (int b = 0; b < 98; ++b){ const int t = bsums[b]; bsums[b] = acc; acc += t; }
  }
}

__global__ void __launch_bounds__(512) scanC_kernel(
    int* __restrict__ cur, const int* __restrict__ bsums)
{
  const int i = blockIdx.x*512 + threadIdx.x;
  if (i < NN) cur[i] += bsums[blockIdx.x];
}

__global__ void __launch_bounds__(512) fill_kernel(
    const int* __restrict__ ei, int* __restrict__ cur, int* __restrict__ perm)
{
  const int e = blockIdx.x*512 + threadIdx.x;
  if (e < NE){
    const int p = atomicAdd(&cur[ei[NE + e]], 1);
    perm[p] = e;
  }
}

// pregather: materialize per-edge data in perm (dst-sorted) order
// edata[i] = { src, dst, relx, rely, relz, dist, ea0, ea1, ea2, ea3, -, - }
__global__ void __launch_bounds__(256) pregather_kernel(
    const int* __restrict__ ei, const float* __restrict__ x,
    const float* __restrict__ eattr, const int* __restrict__ perm,
    uint32_t* __restrict__ edata)
{
  const int i = blockIdx.x*256 + threadIdx.x;
  if (i >= NE) return;
  const int e = perm[i];
  const int sj = ei[e], dj = ei[NE + e];
  const float ax = x[dj*3+0]-x[sj*3+0];
  const float ay = x[dj*3+1]-x[sj*3+1];
  const float az = x[dj*3+2]-x[sj*3+2];
  const float dd = sqrtf(ax*ax + ay*ay + az*az + 1e-8f);
  const float4 e4 = *reinterpret_cast<const float4*>(eattr + (size_t)e*EF);
  uint32_t* dp = edata + (size_t)i*EDW;
  u32x4 v0 = {(uint32_t)sj, (uint32_t)dj, __float_as_uint(ax), __float_as_uint(ay)};
  u32x4 v1 = {__float_as_uint(az), __float_as_uint(dd), __float_as_uint(e4.x), __float_as_uint(e4.y)};
  u32x4 v2 = {__float_as_uint(e4.z), __float_as_uint(e4.w), 0u, 0u};
  *reinterpret_cast<u32x4*>(dp)     = v0;
  *reinterpret_cast<u32x4*>(dp + 4) = v1;
  *reinterpret_cast<u32x4*>(dp + 8) = v2;
}

// ---------------------------------------------------------------------------
// Edge kernel: 3-barrier phase-pipelined version of R11.
//  - tile t+1 staging (h-gather + geometry + gauss) runs between barrier A
//    and B, overlapped with GEMM2/scatter/GEMM3 via wave TLP; per-tile state
//    (rel/dist/pe/pg/runs) ping-pongs in tl[2] so no loop-top barrier needed.
//  - mi scatter: per-wave redundant s_eij precompute (no barrier), hoisted
//    mf_ index algebra; dx scatter wave-0-only with per-row scale precompute.
// 8 waves/block, tile = 64 dst-sorted edges; wave w owns cols 16w..16w+15.
// A-frag: lane l holds row l&15, k = 32ks + 8*(l>>4) + j.
// D-frag: row(m)=4*(l>>4)+reg, col(n)=l&15.
// tl block (u32 offsets): rel[0..192) dist[192..256) pe[256..320) pg[320..384)
//   udst[384..448) ustart[448..514) (ustart[65]=U)
// ---------------------------------------------------------------------------
#define EDGE_LDS_U32 (64*ROWU + 4096 + 4096 + 2*TLW + 64)
#define EDGE_LDS_B (EDGE_LDS_U32*4)   // 75072 B -> 2 blocks/CU

__global__ void __launch_bounds__(512, 4) edge_red_kernel(
    const uint32_t* __restrict__ hb, const uint32_t* __restrict__ edata,
    const float* __restrict__ We1, const float* __restrict__ be1,
    const float* __restrict__ We2, const float* __restrict__ be2,
    const float* __restrict__ Winf, const float* __restrict__ binf,
    const float* __restrict__ Wx1, const float* __restrict__ bx1,
    const float* __restrict__ Wx2, float* __restrict__ out)
{
  extern __shared__ uint32_t smem[];
  uint32_t* s_inp = smem;                                   // [64][ROWU]
  uint16_t* t1f   = (uint16_t*)(smem + 64*ROWU);            // [16][64][8] u16
  uint16_t* mf_   = (uint16_t*)(smem + 64*ROWU + 4096);     // [16][64][8] u16
  uint32_t* tlb   = smem + 64*ROWU + 8192;                  // tl[2]
  float*    s_eij = (float*)(smem + 64*ROWU + 8192 + 2*TLW);// 64 (scratch)

  const int tid = threadIdx.x;
  const int w = tid >> 6, l = tid & 63;
  const int lo = l & 15, hi = l >> 4;
  const int col = w*16 + lo;
  const int r8 = tid >> 3, p8 = tid & 7;
  const int ks2 = w >> 1;
  const int lp  = ((w&1)*2 + (lo>>3))*16 + 4*hi;
  const int jj  = lo & 7;
  const int lsw = SW(l);

  // ---- persistent weight B-fragments (17 frags = 68 regs) ----
  u32x4 B1[9], B2[4], B3[4];
  #pragma unroll
  for (int ks = 0; ks < 9; ++ks){
    float f[8];
    #pragma unroll
    for (int j = 0; j < 8; ++j){
      const int k = ks*32 + hi*8 + j;
      f[j] = (k < K1) ? We1[k*HD + col] : 0.0f;
    }
    B1[ks] = {pk2(f[0],f[1]), pk2(f[2],f[3]), pk2(f[4],f[5]), pk2(f[6],f[7])};
  }
  #pragma unroll
  for (int ks = 0; ks < 4; ++ks){
    float f2[8], f3[8];
    #pragma unroll
    for (int j = 0; j < 8; ++j){
      const int k = ks*32 + hi*8 + j;
      f2[j] = We2[k*HD + col];
      f3[j] = Wx1[k*HD + col];
    }
    B2[ks] = {pk2(f2[0],f2[1]), pk2(f2[2],f2[3]), pk2(f2[4],f2[5]), pk2(f2[6],f2[7])};
    B3[ks] = {pk2(f3[0],f3[1]), pk2(f3[2],f3[3]), pk2(f3[4],f3[5]), pk2(f3[6],f3[7])};
  }
  const float vbe1 = be1[col], vbe2 = be2[col], vbx1 = bx1[col];
  const float wi = Winf[col], wx = Wx2[col], vbinf = binf[0];
  const float SP = 10.0f/19.0f;
  const float CO = -0.5f/(SP*SP);

  // stage: gather h rows + geometry/runs/gauss for tile at edge-base nb
  auto stage = [&](int nb, uint32_t* tq){
    { // all threads: bf16 h-row gather (issue loads first)
      const uint32_t node = edata[(size_t)(nb + r8)*EDW + (p8 < 4 ? 1 : 0)];
      const uint32_t* hw = hb + (size_t)node*(HD/2) + (p8&3)*16;
      uint32_t* dp = s_inp + r8*ROWU + p8*16;
      #pragma unroll
      for (int q = 0; q < 4; ++q)
        *reinterpret_cast<u32x4*>(dp + 4*q) = *reinterpret_cast<const u32x4*>(hw + 4*q);
    }
    if (tid < 64){  // wave 0: geometry, run table, gauss cols
      float* q_rel  = (float*)(tq);
      float* q_dist = (float*)(tq+192);
      float* q_pe   = (float*)(tq+256);
      float* q_pg   = (float*)(tq+320);
      int*   q_udst = (int*)(tq+384);
      int*   q_ust  = (int*)(tq+448);
      const uint32_t* ed = edata + (size_t)(nb + tid)*EDW;
      const u32x4 w0 = *reinterpret_cast<const u32x4*>(ed);
      const u32x4 w1 = *reinterpret_cast<const u32x4*>(ed + 4);
      const u32x4 w2 = *reinterpret_cast<const u32x4*>(ed + 8);
      const int dj   = (int)w0.y;
      const float ax = __uint_as_float(w0.z);
      const float ay = __uint_as_float(w0.w);
      const float az = __uint_as_float(w1.x);
      const float dd = __uint_as_float(w1.y);
      q_rel[3*tid+0]=ax; q_rel[3*tid+1]=ay; q_rel[3*tid+2]=az;
      q_dist[tid]=dd; q_pe[tid]=0.0f; q_pg[tid]=0.0f;
      const int dprev = __shfl_up(dj, 1);
      const int isnew = (tid == 0) || (dj != dprev);
      const unsigned long long mball = __ballot(isnew);
      const int slot = __popcll(mball << (63 - tid)) - 1;
      if (isnew){ q_udst[slot] = dj; q_ust[slot] = tid; }
      if (tid == 63){ q_ust[slot + 1] = 64; q_ust[65] = slot + 1; }
      float g[24];
      #pragma unroll
      for (int j = 0; j < 20; ++j){ const float a = dd - j*SP; g[j] = __expf(CO*a*a); }
      g[20]=__uint_as_float(w1.z); g[21]=__uint_as_float(w1.w);
      g[22]=__uint_as_float(w2.x); g[23]=__uint_as_float(w2.y);
      uint32_t* gp = s_inp + tid*ROWU + 128;
      u32x4 g0v = {pk2(g[0],g[1]),  pk2(g[2],g[3]),  pk2(g[4],g[5]),  pk2(g[6],g[7])};
      u32x4 g1v = {pk2(g[8],g[9]),  pk2(g[10],g[11]),pk2(g[12],g[13]),pk2(g[14],g[15])};
      u32x4 g2v = {pk2(g[16],g[17]),pk2(g[18],g[19]),pk2(g[20],g[21]),pk2(g[22],g[23])};
      u32x4 g3v = {0,0,0,0};
      *reinterpret_cast<u32x4*>(gp)    = g0v;
      *reinterpret_cast<u32x4*>(gp+4)  = g1v;
      *reinterpret_cast<u32x4*>(gp+8)  = g2v;
      *reinterpret_cast<u32x4*>(gp+12) = g3v;
    }
  };

  // prologue: stage first tile
  stage(blockIdx.x*64, tlb);
  __syncthreads();

  int p = 0;
  for (int t = blockIdx.x; t < TILES; t += EGRID, p ^= 1){
    uint32_t* tlp = tlb + p*TLW;
    float* s_rel  = (float*)(tlp);
    float* s_dist = (float*)(tlp+192);
    float* s_pe   = (float*)(tlp+256);
    float* s_pg   = (float*)(tlp+320);
    int*   s_udst = (int*)(tlp+384);
    int*   s_ust  = (int*)(tlp+448);

    // ---------------- GEMM1: t1 = silu(inp @ We1 + be1) ----------------
    #pragma unroll
    for (int Mt = 0; Mt < 4; ++Mt){
      const uint32_t* arow = s_inp + (Mt*16 + lo)*ROWU + hi*4;
      f32x4 acc = {0,0,0,0};
      #pragma unroll
      for (int ks = 0; ks < 9; ++ks)
        acc = MF(*reinterpret_cast<const u32x4*>(arow + ks*16), B1[ks], acc);
      #pragma unroll
      for (int reg = 0; reg < 4; ++reg)
        t1f[((Mt*4 + ks2)*64 + SW(lp+reg))*8 + jj] = bfb(silu_f(acc[reg] + vbe1));
    }
    __syncthreads();               // A: t1f ready, s_inp(t) dead

    // ---- stage tile t+1 (overlaps GEMM2/scatter/GEMM3 via TLP) ----
    if (t + EGRID < TILES) stage((t + EGRID)*64, tlb + (p^1)*TLW);

    // ---------------- GEMM2: mij = silu(t1 @ We2 + be2); eij partials ----
    #pragma unroll
    for (int Mt = 0; Mt < 4; ++Mt){
      f32x4 acc = {0,0,0,0};
      #pragma unroll
      for (int ks = 0; ks < 4; ++ks)
        acc = MF(*reinterpret_cast<const u32x4*>(t1f + ((Mt*4+ks)*64 + lsw)*8), B2[ks], acc);
      float pq[4];
      #pragma unroll
      for (int reg = 0; reg < 4; ++reg){
        const float m = silu_f(acc[reg] + vbe2);
        mf_[((Mt*4 + ks2)*64 + SW(lp+reg))*8 + jj] = bfb(m);
        pq[reg] = m * wi;
      }
      #pragma unroll
      for (int msk = 1; msk < 16; msk <<= 1){
        #pragma unroll
        for (int reg = 0; reg < 4; ++reg) pq[reg] += __shfl_xor(pq[reg], msk);
      }
      if (lo == 0){
        #pragma unroll
        for (int reg = 0; reg < 4; ++reg) atomicAdd(&s_pe[Mt*16 + 4*hi + reg], pq[reg]);
      }
    }
    __syncthreads();               // B: mf_ + s_pe ready

    // ---- per-wave redundant eij precompute (no barrier: each wave's own
    //      64 lanes write all 64 entries before that wave reads them) ----
    s_eij[l] = sigmoid_f(s_pe[l] + vbinf);
    const int U = s_ust[65];

    // ---- mi run-reduced scatter: one thread per (run u, col c) output ----
    for (int idx = tid; idx < U*HD; idx += 512){
      const int u = idx >> 7, c = idx & 127;
      const int r0 = s_ust[u], r1 = s_ust[u+1];
      const int cb = c >> 5, cc = ((c>>4)&1)*2 + ((c>>3)&1);
      const int base = (cb*64 + cc*16)*8 + (c & 7);
      const int x2 = cc*2;
      float acc = 0.0f;
      for (int r = r0; r < r1; ++r){
        const int mix = (r>>4)*2048 + base + (((r&15) ^ ((x2 + ((r>>3)&1))&7))<<3);
        acc += bf2f(mf_[mix]) * s_eij[r];
      }
      atomicAdd(out + (size_t)s_udst[u]*HD + c, acc);
    }
    // ---------------- GEMM3: gate partials (hides atomic latency) --------
    #pragma unroll
    for (int Mt = 0; Mt < 4; ++Mt){
      f32x4 acc = {0,0,0,0};
      #pragma unroll
      for (int ks = 0; ks < 4; ++ks)
        acc = MF(*reinterpret_cast<const u32x4*>(mf_ + ((Mt*4+ks)*64 + lsw)*8), B3[ks], acc);
      float pq[4];
      #pragma unroll
      for (int reg = 0; reg < 4; ++reg)
        pq[reg] = silu_f(acc[reg] + vbx1) * wx;
      #pragma unroll
      for (int msk = 1; msk < 16; msk <<= 1){
        #pragma unroll
        for (int reg = 0; reg < 4; ++reg) pq[reg] += __shfl_xor(pq[reg], msk);
      }
      if (lo == 0){
        #pragma unroll
        for (int reg = 0; reg < 4; ++reg) atomicAdd(&s_pg[Mt*16 + 4*hi + reg], pq[reg]);
      }
    }
    __syncthreads();               // D: s_pg ready; stage(t+1) writes visible

    // ---- dx run-reduced scatter (wave 0 only; wave-internal precompute) ----
    if (tid < 64){
      s_eij[tid] = tanh_f(s_pg[tid]) * fast_rcp(s_dist[tid] + 1.0f);
      for (int idx = tid; idx < U*3; idx += 64){
        const int u = idx/3, cc2 = idx - 3*u;
        float acc = 0.0f;
        for (int r = s_ust[u]; r < s_ust[u+1]; ++r)
          acc += s_rel[3*r+cc2] * s_eij[r];
        atomicAdd(out + (size_t)NN*HD + (size_t)s_udst[u]*3 + cc2, acc);
      }
    }
    // no loop-top barrier: GEMM1(t+1) reads s_inp staged before D; t1f last
    // read before D; dx (wave 0) and stage(t+2) (wave 0) are program-ordered.
  }
}

// ---------------------------------------------------------------------------
// Fallback edge kernel (round 6, f32-h, unsorted per-edge atomics).
// ---------------------------------------------------------------------------
#define FB_LDS_U32 (64*ROWU + 4096 + 4096 + 448)
#define FB_LDS_B (FB_LDS_U32*4)

__global__ void __launch_bounds__(512, 4) edge_fb_kernel(
    const float* __restrict__ h, const float* __restrict__ x,
    const int* __restrict__ ei, const float* __restrict__ eattr,
    const float* __restrict__ We1, const float* __restrict__ be1,
    const float* __restrict__ We2, const float* __restrict__ be2,
    const float* __restrict__ Winf, const float* __restrict__ binf,
    const float* __restrict__ Wx1, const float* __restrict__ bx1,
    const float* __restrict__ Wx2, float* __restrict__ out)
{
  extern __shared__ uint32_t smem[];
  uint32_t* s_inp = smem;
  uint16_t* t1f   = (uint16_t*)(smem + 64*ROWU);
  uint16_t* mf_   = (uint16_t*)(smem + 64*ROWU + 4096);
  uint32_t* tl    = smem + 64*ROWU + 8192;
  int*   s_dst  = (int*)tl;
  float* s_rel  = (float*)(tl+64);
  float* s_dist = (float*)(tl+256);
  float* s_pe   = (float*)(tl+320);
  float* s_pg   = (float*)(tl+384);

  const int tid = threadIdx.x;
  const int w = tid >> 6, l = tid & 63;
  const int lo = l & 15, hi = l >> 4;
  const int col = w*16 + lo;
  const int r8 = tid >> 3, p8 = tid & 7;
  const int ks2 = w >> 1;
  const int lp  = ((w&1)*2 + (lo>>3))*16 + 4*hi;
  const int jj  = lo & 7;
  const int lsw = SW(l);

  u32x4 B1[9], B2[4], B3[4];
  #pragma unroll
  for (int ks = 0; ks < 9; ++ks){
    float f[8];
    #pragma unroll
    for (int j = 0; j < 8; ++j){
      const int k = ks*32 + hi*8 + j;
      f[j] = (k < K1) ? We1[k*HD + col] : 0.0f;
    }
    B1[ks] = {pk2(f[0],f[1]), pk2(f[2],f[3]), pk2(f[4],f[5]), pk2(f[6],f[7])};
  }
  #pragma unroll
  for (int ks = 0; ks < 4; ++ks){
    float f2[8], f3[8];
    #pragma unroll
    for (int j = 0; j < 8; ++j){
      const int k = ks*32 + hi*8 + j;
      f2[j] = We2[k*HD + col];
      f3[j] = Wx1[k*HD + col];
    }
    B2[ks] = {pk2(f2[0],f2[1]), pk2(f2[2],f2[3]), pk2(f2[4],f2[5]), pk2(f2[6],f2[7])};
    B3[ks] = {pk2(f3[0],f3[1]), pk2(f3[2],f3[3]), pk2(f3[4],f3[5]), pk2(f3[6],f3[7])};
  }
  const float vbe1 = be1[col], vbe2 = be2[col], vbx1 = bx1[col];
  const float wi = Winf[col], wx = Wx2[col], vbinf = binf[0];
  const float SP = 10.0f/19.0f;
  const float CO = -0.5f/(SP*SP);

  for (int t = blockIdx.x; t < TILES; t += EGRID){
    const int ebase = t*64;
    __syncthreads();
    if (tid < 64){
      const int sj = ei[ebase+tid], dj = ei[NE+ebase+tid];
      const float ax = x[dj*3+0]-x[sj*3+0];
      const float ay = x[dj*3+1]-x[sj*3+1];
      const float az = x[dj*3+2]-x[sj*3+2];
      const float dd = sqrtf(ax*ax + ay*ay + az*az + 1e-8f);
      s_dst[tid] = dj;
      s_rel[3*tid+0]=ax; s_rel[3*tid+1]=ay; s_rel[3*tid+2]=az;
      s_dist[tid]=dd; s_pe[tid]=0.0f; s_pg[tid]=0.0f;
      float g[24];
      #pragma unroll
      for (int j = 0; j < 20; ++j){ const float a = dd - j*SP; g[j] = __expf(CO*a*a); }
      const float4 e4 = *reinterpret_cast<const float4*>(eattr + (size_t)(ebase+tid)*EF);
      g[20]=e4.x; g[21]=e4.y; g[22]=e4.z; g[23]=e4.w;
      uint32_t* gp = s_inp + tid*ROWU + 128;
      u32x4 g0v = {pk2(g[0],g[1]),  pk2(g[2],g[3]),  pk2(g[4],g[5]),  pk2(g[6],g[7])};
      u32x4 g1v = {pk2(g[8],g[9]),  pk2(g[10],g[11]),pk2(g[12],g[13]),pk2(g[14],g[15])};
      u32x4 g2v = {pk2(g[16],g[17]),pk2(g[18],g[19]),pk2(g[20],g[21]),pk2(g[22],g[23])};
      u32x4 g3v = {0,0,0,0};
      *reinterpret_cast<u32x4*>(gp)    = g0v;
      *reinterpret_cast<u32x4*>(gp+4)  = g1v;
      *reinterpret_cast<u32x4*>(gp+8)  = g2v;
      *reinterpret_cast<u32x4*>(gp+12) = g3v;
    }
    {
      const int e = ebase + r8;
      const int node = (p8 < 4) ? ei[NE + e] : ei[e];
      const float* hp = h + (size_t)node*HD + (p8&3)*32;
      uint32_t* dp = s_inp + r8*ROWU + p8*16;
      #pragma unroll
      for (int q = 0; q < 4; ++q){
        const float4 va = *reinterpret_cast<const float4*>(hp + 8*q);
        const float4 vb = *reinterpret_cast<const float4*>(hp + 8*q + 4);
        u32x4 v = { pk2(va.x,va.y), pk2(va.z,va.w), pk2(vb.x,vb.y), pk2(vb.z,vb.w) };
        *reinterpret_cast<u32x4*>(dp + 4*q) = v;
      }
    }
    __syncthreads();

    #pragma unroll
    for (int Mt = 0; Mt < 4; ++Mt){
      const uint32_t* arow = s_inp + (Mt*16 + lo)*ROWU + hi*4;
      f32x4 acc = {0,0,0,0};
      #pragma unroll
      for (int ks = 0; ks < 9; ++ks)
        acc = MF(*reinterpret_cast<const u32x4*>(arow + ks*16), B1[ks], acc);
      #pragma unroll
      for (int reg = 0; reg < 4; ++reg)
        t1f[((Mt*4 + ks2)*64 + SW(lp+reg))*8 + jj] = bfb(silu_f(acc[reg] + vbe1));
    }
    __syncthreads();

    #pragma unroll
    for (int Mt = 0; Mt < 4; ++Mt){
      f32x4 acc = {0,0,0,0};
      #pragma unroll
      for (int ks = 0; ks < 4; ++ks)
        acc = MF(*reinterpret_cast<const u32x4*>(t1f + ((Mt*4+ks)*64 + lsw)*8), B2[ks], acc);
      float pq[4];
      #pragma unroll
      for (int reg = 0; reg < 4; ++reg){
        const float m = silu_f(acc[reg] + vbe2);
        mf_[((Mt*4 + ks2)*64 + SW(lp+reg))*8 + jj] = bfb(m);
        pq[reg] = m * wi;
      }
      #pragma unroll
      for (int msk = 1; msk < 16; msk <<= 1){
        #pragma unroll
        for (int reg = 0; reg < 4; ++reg) pq[reg] += __shfl_xor(pq[reg], msk);
      }
      if (lo == 0){
        #pragma unroll
        for (int reg = 0; reg < 4; ++reg) atomicAdd(&s_pe[Mt*16 + 4*hi + reg], pq[reg]);
      }
    }
    __syncthreads();

    #pragma unroll
    for (int Mt = 0; Mt < 4; ++Mt){
      #pragma unroll
      for (int reg = 0; reg < 4; ++reg){
        const int r = Mt*16 + 4*hi + reg;
        const float eij = sigmoid_f(s_pe[r] + vbinf);
        const float m = bf2f(mf_[((Mt*4 + ks2)*64 + SW(lp+reg))*8 + jj]);
        atomicAdd(out + (size_t)s_dst[r]*HD + col, m*eij);
      }
    }
    #pragma unroll
    for (int Mt = 0; Mt < 4; ++Mt){
      f32x4 acc = {0,0,0,0};
      #pragma unroll
      for (int ks = 0; ks < 4; ++ks)
        acc = MF(*reinterpret_cast<const u32x4*>(mf_ + ((Mt*4+ks)*64 + lsw)*8), B3[ks], acc);
      float pq[4];
      #pragma unroll
      for (int reg = 0; reg < 4; ++reg)
        pq[reg] = silu_f(acc[reg] + vbx1) * wx;
      #pragma unroll
      for (int msk = 1; msk < 16; msk <<= 1){
        #pragma unroll
        for (int reg = 0; reg < 4; ++reg) pq[reg] += __shfl_xor(pq[reg], msk);
      }
      if (lo == 0){
        #pragma unroll
        for (int reg = 0; reg < 4; ++reg) atomicAdd(&s_pg[Mt*16 + 4*hi + reg], pq[reg]);
      }
    }
    __syncthreads();

    if (tid < 192){
      const int er = tid/3, c = tid - 3*er;
      const float gate = tanh_f(s_pg[er]);
      const float sc = gate * fast_rcp(s_dist[er] + 1.0f);
      atomicAdd(out + (size_t)NN*HD + (size_t)s_dst[er]*3 + c, s_rel[3*er+c]*sc);
    }
  }
}

// ---------------------------------------------------------------------------
// Node kernel (MFMA), unchanged.
// ---------------------------------------------------------------------------
#define CROW 132

__global__ void __launch_bounds__(512, 4) node_kernel(
    const float* __restrict__ h, const float* __restrict__ x,
    const float* __restrict__ mask,
    const float* __restrict__ Wn1, const float* __restrict__ bn1,
    const float* __restrict__ Wn2, const float* __restrict__ bn2,
    float* __restrict__ out)
{
  __shared__ uint32_t s_cat[64*CROW];
  __shared__ __align__(16) uint16_t t1n[4*4*64*8];

  const int tid = threadIdx.x;
  const int w = tid >> 6, l = tid & 63;
  const int lo = l & 15, hi = l >> 4;
  const int col = w*16 + lo;

  u32x4 Bn1[8], Bn2[4];
  #pragma unroll
  for (int ks = 0; ks < 8; ++ks){
    float f[8];
    #pragma unroll
    for (int j = 0; j < 8; ++j) f[j] = Wn1[(ks*32 + hi*8 + j)*HD + col];
    Bn1[ks] = {pk2(f[0],f[1]), pk2(f[2],f[3]), pk2(f[4],f[5]), pk2(f[6],f[7])};
  }
  #pragma unroll
  for (int ks = 0; ks < 4; ++ks){
    float f[8];
    #pragma unroll
    for (int j = 0; j < 8; ++j) f[j] = Wn2[(ks*32 + hi*8 + j)*HD + col];
    Bn2[ks] = {pk2(f[0],f[1]), pk2(f[2],f[3]), pk2(f[4],f[5]), pk2(f[6],f[7])};
  }
  const float vbn1 = bn1[col], vbn2 = bn2[col];
  const int nbase = blockIdx.x*64;
  const int ks2 = w >> 1;
  const int lp  = ((w&1)*2 + (lo>>3))*16 + 4*hi;
  const int jj  = lo & 7;

  {
    const int r = tid >> 3, p = tid & 7;
    const int n = nbase + r;
    uint32_t* dp = s_cat + r*CROW + p*16;
    if (n < NN){
      const float* sp = (p < 4) ? (out + (size_t)n*HD + p*32)
                                : (h   + (size_t)n*HD + (p-4)*32);
      #pragma unroll
      for (int q = 0; q < 8; ++q){
        const float4 v = *reinterpret_cast<const float4*>(sp + 4*q);
        dp[2*q]   = pk2(v.x, v.y);
        dp[2*q+1] = pk2(v.z, v.w);
      }
    } else {
      #pragma unroll
      for (int q = 0; q < 16; ++q) dp[q] = 0u;
    }
  }
  __syncthreads();

  #pragma unroll
  for (int Mt = 0; Mt < 4; ++Mt){
    const uint32_t* arow = s_cat + (Mt*16 + lo)*CROW + hi*4;
    f32x4 acc = {0,0,0,0};
    #pragma unroll
    for (int ks = 0; ks < 8; ++ks)
      acc = MF(*reinterpret_cast<const u32x4*>(arow + ks*16), Bn1[ks], acc);
    uint16_t* tp = t1n + ((Mt*4 + ks2)*64 + lp)*8 + jj;
    #pragma unroll
    for (int reg = 0; reg < 4; ++reg)
      tp[reg*8] = bfb(silu_f(acc[reg] + vbn1));
  }
  __syncthreads();

  #pragma unroll
  for (int Mt = 0; Mt < 4; ++Mt){
    f32x4 acc = {0,0,0,0};
    #pragma unroll
    for (int ks = 0; ks < 4; ++ks)
      acc = MF(*reinterpret_cast<const u32x4*>(t1n + ((Mt*4+ks)*64 + l)*8), Bn2[ks], acc);
    #pragma unroll
    for (int reg = 0; reg < 4; ++reg){
      const int n = nbase + Mt*16 + 4*hi + reg;
      if (n < NN)
        out[(size_t)n*HD + col] = h[(size_t)n*HD + col] + acc[reg] + vbn2;
    }
  }

  if (tid < 192){
    const int r = tid/3, c = tid - 3*r;
    const int n = nbase + r;
    if (n < NN){
      const size_t ix = (size_t)NN*HD + (size_t)n*3 + c;
      out[ix] = x[(size_t)n*3 + c] + out[ix]*mask[n];
    }
  }
}

extern "C" void kernel_launch(void* const* d_in, const int* in_sizes, int n_in,
                              void* d_out, int out_size, void* d_ws, size_t ws_size,
                              hipStream_t stream) {
  (void)in_sizes; (void)n_in;
  const float* h    = (const float*)d_in[0];
  const float* x    = (const float*)d_in[1];
  const int*   ei   = (const int*)  d_in[2];
  const float* mask = (const float*)d_in[3];
  const float* ea   = (const float*)d_in[4];
  const float* We1  = (const float*)d_in[5];
  const float* be1  = (const float*)d_in[6];
  const float* We2  = (const float*)d_in[7];
  const float* be2  = (const float*)d_in[8];
  const float* Winf = (const float*)d_in[9];
  const float* binf = (const float*)d_in[10];
  const float* Wx1  = (const float*)d_in[11];
  const float* bx1  = (const float*)d_in[12];
  const float* Wx2  = (const float*)d_in[13];
  const float* Wn1  = (const float*)d_in[14];
  const float* bn1  = (const float*)d_in[15];
  const float* Wn2  = (const float*)d_in[16];
  const float* bn2  = (const float*)d_in[17];
  float* out = (float*)d_out;

  // ws layout (u32): hb[3.2M] | cursor[50k] | perm[600k] | bsums[128] | edata[7.2M]
  uint32_t* hb    = (uint32_t*)d_ws;
  int* cursor     = (int*)d_ws + 3200000;
  int* perm       = (int*)d_ws + 3250000;
  int* bsums      = (int*)d_ws + 3850000;
  uint32_t* edata = (uint32_t*)d_ws + 3850128;
  const size_t need = (size_t)(3850128 + (size_t)NE*EDW) * 4;   // ~44.2 MB
  const bool use_red = ws_size >= need;

  hipFuncSetAttribute(reinterpret_cast<const void*>(edge_red_kernel),
                      hipFuncAttributeMaxDynamicSharedMemorySize, EDGE_LDS_B);
  hipFuncSetAttribute(reinterpret_cast<const void*>(edge_fb_kernel),
                      hipFuncAttributeMaxDynamicSharedMemorySize, FB_LDS_B);

  // out[0..NN*HD) accumulates mi; out[NN*HD..) accumulates delta_x
  hipMemsetAsync(d_out, 0, (size_t)out_size * sizeof(float), stream);

  if (use_red){
    hipMemsetAsync(cursor, 0, (size_t)NN*4, stream);
    h2bf_kernel<<<3125, 256, 0, stream>>>(h, hb);
    hist_kernel<<<1172, 512, 0, stream>>>(ei, cursor);
    scanA_kernel<<<98, 512, 0, stream>>>(cursor, bsums);
    scanB_kernel<<<1, 64, 0, stream>>>(bsums);
    scanC_kernel<<<98, 512, 0, stream>>>(cursor, bsums);
    fill_kernel<<<1172, 512, 0, stream>>>(ei, cursor, perm);
    pregather_kernel<<<2344, 256, 0, stream>>>(ei, x, ea, perm, edata);
    edge_red_kernel<<<EGRID, 512, EDGE_LDS_B, stream>>>(
        hb, edata, We1, be1, We2, be2, Winf, binf, Wx1, bx1, Wx2, out);
  } else {
    edge_fb_kernel<<<EGRID, 512, FB_LDS_B, stream>>>(
        h, x, ei, ea, We1, be1, We2, be2, Winf, binf, Wx1, bx1, Wx2, out);
  }
  node_kernel<<<NTILE, 512, 0, stream>>>(
      h, x, mask, Wn1, bn1, Wn2, bn2, out);
}

// Round 13
// 427.860 us; speedup vs baseline: 2.5400x; 1.0617x over previous
//
#include <hip/hip_runtime.h>
#include <hip/hip_bf16.h>
#include <cstdint>

// Problem constants (EnBaseLayer: E(n)-GNN layer)
#define NN 50000
#define NE 600000
#define HD 128
#define NG 20
#define EF 4
#define K1 280            // 2H + NG + EF
#define TILES (NE/64)     // 9375
#define EGRID 512         // 2 blocks/CU resident
#define ROWU 148          // s_inp row stride in u32 (592 B = 37*16)
#define NTILE 782         // ceil(NN/64)
#define SW(r) ((r) ^ (((r)>>3)&7))   // LDS 16B-slot swizzle within 8-row group
#define EDW 12            // edata u32 words per edge
#define TLW 584           // per-tile tl block size in u32 (ping-pong)

typedef __attribute__((ext_vector_type(4))) float f32x4;
typedef __attribute__((ext_vector_type(8))) __bf16 bf16x8;
typedef __attribute__((ext_vector_type(4))) unsigned int u32x4;

__device__ __forceinline__ float fast_rcp(float x){ return __builtin_amdgcn_rcpf(x); }
__device__ __forceinline__ float silu_f(float x){ return x * fast_rcp(1.0f + __expf(-x)); }
__device__ __forceinline__ float sigmoid_f(float x){ return fast_rcp(1.0f + __expf(-x)); }
__device__ __forceinline__ float tanh_f(float x){ return 1.0f - 2.0f*fast_rcp(__expf(2.0f*x)+1.0f); }

__device__ __forceinline__ uint32_t pk2(float a, float b){   // RNE f32x2 -> bf16x2
  uint32_t ua = __float_as_uint(a); ua += 0x7FFFu + ((ua>>16)&1u);
  uint32_t ub = __float_as_uint(b); ub += 0x7FFFu + ((ub>>16)&1u);
  return (ua>>16) | (ub & 0xFFFF0000u);
}
__device__ __forceinline__ uint16_t bfb(float a){
  uint32_t ua = __float_as_uint(a); ua += 0x7FFFu + ((ua>>16)&1u);
  return (uint16_t)(ua>>16);
}
__device__ __forceinline__ float bf2f(uint16_t b){ return __uint_as_float(((uint32_t)b)<<16); }
__device__ __forceinline__ f32x4 MF(u32x4 a, u32x4 b, f32x4 c){
  return __builtin_amdgcn_mfma_f32_16x16x32_bf16(
      __builtin_bit_cast(bf16x8, a), __builtin_bit_cast(bf16x8, b), c, 0, 0, 0);
}

// ---------------------------------------------------------------------------
// Pre-kernels (fused): h->bf16 + dst histogram; block scan; prefix+add;
// fill+pregather (writes edata directly in dst-sorted position, no perm).
// ---------------------------------------------------------------------------
__global__ void __launch_bounds__(512) h2bf_hist_kernel(
    const float* __restrict__ h, uint32_t* __restrict__ hb,
    const int* __restrict__ ei, int* __restrict__ cnt)
{
  const int gid = blockIdx.x*512 + threadIdx.x;
  if (gid < 800000){
    const size_t i = (size_t)gid*8;
    const float4 a = *reinterpret_cast<const float4*>(h + i);
    const float4 b = *reinterpret_cast<const float4*>(h + i + 4);
    u32x4 v = {pk2(a.x,a.y), pk2(a.z,a.w), pk2(b.x,b.y), pk2(b.z,b.w)};
    *reinterpret_cast<u32x4*>(hb + i/2) = v;
  }
  if (gid < NE) atomicAdd(&cnt[ei[NE + gid]], 1);
}

__global__ void __launch_bounds__(512) scanA_kernel(
    int* __restrict__ cur, int* __restrict__ bsums)
{
  __shared__ int s[512];
  const int tid = threadIdx.x;
  const int i = blockIdx.x*512 + tid;
  const int v = (i < NN) ? cur[i] : 0;
  s[tid] = v; __syncthreads();
  #pragma unroll
  for (int d = 1; d < 512; d <<= 1){
    const int t = (tid >= d) ? s[tid-d] : 0;
    __syncthreads();
    s[tid] += t;
    __syncthreads();
  }
  if (i < NN) cur[i] = s[tid] - v;             // exclusive within block
  if (tid == 511) bsums[blockIdx.x] = s[511];  // block total
}

__global__ void __launch_bounds__(512) scanBC_kernel(
    int* __restrict__ cur, const int* __restrict__ bsums)
{
  __shared__ int pre;
  if (threadIdx.x == 0){
    int acc = 0;
    for (int b = 0; b < (int)blockIdx.x; ++b) acc += bsums[b];
    pre = acc;
  }
  __syncthreads();
  const int i = blockIdx.x*512 + threadIdx.x;
  if (i < NN) cur[i] += pre;
}

// fused fill+pregather: place edge e at its dst-sorted slot p and write the
// materialized edge record there directly (perm array eliminated).
// edata[p] = { src, dst, relx, rely, relz, dist, ea0, ea1, ea2, ea3, -, - }
__global__ void __launch_bounds__(256) fillpg_kernel(
    const int* __restrict__ ei, const float* __restrict__ x,
    const float* __restrict__ eattr, int* __restrict__ cur,
    uint32_t* __restrict__ edata)
{
  const int e = blockIdx.x*256 + threadIdx.x;
  if (e >= NE) return;
  const int sj = ei[e], dj = ei[NE + e];
  const int p = atomicAdd(&cur[dj], 1);
  const float ax = x[dj*3+0]-x[sj*3+0];
  const float ay = x[dj*3+1]-x[sj*3+1];
  const float az = x[dj*3+2]-x[sj*3+2];
  const float dd = sqrtf(ax*ax + ay*ay + az*az + 1e-8f);
  const float4 e4 = *reinterpret_cast<const float4*>(eattr + (size_t)e*EF);
  uint32_t* dp = edata + (size_t)p*EDW;
  u32x4 v0 = {(uint32_t)sj, (uint32_t)dj, __float_as_uint(ax), __float_as_uint(ay)};
  u32x4 v1 = {__float_as_uint(az), __float_as_uint(dd), __float_as_uint(e4.x), __float_as_uint(e4.y)};
  u32x4 v2 = {__float_as_uint(e4.z), __float_as_uint(e4.w), 0u, 0u};
  *reinterpret_cast<u32x4*>(dp)     = v0;
  *reinterpret_cast<u32x4*>(dp + 4) = v1;
  *reinterpret_cast<u32x4*>(dp + 8) = v2;
}

// ---------------------------------------------------------------------------
// Edge kernel: 3-barrier pipelined (R12) + load-balanced run-flush scatter.
//  - mi scatter: thread owns (row-group rb, col c); walks its 16 sorted rows
//    accumulating, flushes on slot change -> exactly 16 products/thread,
//    wave-uniform branch, contention-free atomics, hidden under GEMM3.
// 8 waves/block, tile = 64 dst-sorted edges; wave w owns cols 16w..16w+15.
// A-frag: lane l holds row l&15, k = 32ks + 8*(l>>4) + j.
// D-frag: row(m)=4*(l>>4)+reg, col(n)=l&15.
// tl block (u32): rel[0..192) dist[192..256) pe[256..320) pg[320..384)
//   udst[384..448) ustart[448..514) (ustart[65]=U) slot[514..578)
// ---------------------------------------------------------------------------
#define EDGE_LDS_U32 (64*ROWU + 4096 + 4096 + 2*TLW + 64)
#define EDGE_LDS_B (EDGE_LDS_U32*4)   // 75584 B -> 2 blocks/CU

__global__ void __launch_bounds__(512, 4) edge_red_kernel(
    const uint32_t* __restrict__ hb, const uint32_t* __restrict__ edata,
    const float* __restrict__ We1, const float* __restrict__ be1,
    const float* __restrict__ We2, const float* __restrict__ be2,
    const float* __restrict__ Winf, const float* __restrict__ binf,
    const float* __restrict__ Wx1, const float* __restrict__ bx1,
    const float* __restrict__ Wx2, float* __restrict__ out)
{
  extern __shared__ uint32_t smem[];
  uint32_t* s_inp = smem;                                   // [64][ROWU]
  uint16_t* t1f   = (uint16_t*)(smem + 64*ROWU);            // [16][64][8] u16
  uint16_t* mf_   = (uint16_t*)(smem + 64*ROWU + 4096);     // [16][64][8] u16
  uint32_t* tlb   = smem + 64*ROWU + 8192;                  // tl[2]
  float*    s_eij = (float*)(smem + 64*ROWU + 8192 + 2*TLW);// 64 (scratch)

  const int tid = threadIdx.x;
  const int w = tid >> 6, l = tid & 63;
  const int lo = l & 15, hi = l >> 4;
  const int col = w*16 + lo;
  const int r8 = tid >> 3, p8 = tid & 7;
  const int ks2 = w >> 1;
  const int lp  = ((w&1)*2 + (lo>>3))*16 + 4*hi;
  const int jj  = lo & 7;
  const int lsw = SW(l);

  // ---- persistent weight B-fragments (17 frags = 68 regs) ----
  u32x4 B1[9], B2[4], B3[4];
  #pragma unroll
  for (int ks = 0; ks < 9; ++ks){
    float f[8];
    #pragma unroll
    for (int j = 0; j < 8; ++j){
      const int k = ks*32 + hi*8 + j;
      f[j] = (k < K1) ? We1[k*HD + col] : 0.0f;
    }
    B1[ks] = {pk2(f[0],f[1]), pk2(f[2],f[3]), pk2(f[4],f[5]), pk2(f[6],f[7])};
  }
  #pragma unroll
  for (int ks = 0; ks < 4; ++ks){
    float f2[8], f3[8];
    #pragma unroll
    for (int j = 0; j < 8; ++j){
      const int k = ks*32 + hi*8 + j;
      f2[j] = We2[k*HD + col];
      f3[j] = Wx1[k*HD + col];
    }
    B2[ks] = {pk2(f2[0],f2[1]), pk2(f2[2],f2[3]), pk2(f2[4],f2[5]), pk2(f2[6],f2[7])};
    B3[ks] = {pk2(f3[0],f3[1]), pk2(f3[2],f3[3]), pk2(f3[4],f3[5]), pk2(f3[6],f3[7])};
  }
  const float vbe1 = be1[col], vbe2 = be2[col], vbx1 = bx1[col];
  const float wi = Winf[col], wx = Wx2[col], vbinf = binf[0];
  const float SP = 10.0f/19.0f;
  const float CO = -0.5f/(SP*SP);

  // stage: gather h rows + geometry/runs/gauss for tile at edge-base nb
  auto stage = [&](int nb, uint32_t* tq){
    { // all threads: bf16 h-row gather
      const uint32_t node = edata[(size_t)(nb + r8)*EDW + (p8 < 4 ? 1 : 0)];
      const uint32_t* hw = hb + (size_t)node*(HD/2) + (p8&3)*16;
      uint32_t* dp = s_inp + r8*ROWU + p8*16;
      #pragma unroll
      for (int q = 0; q < 4; ++q)
        *reinterpret_cast<u32x4*>(dp + 4*q) = *reinterpret_cast<const u32x4*>(hw + 4*q);
    }
    if (tid < 64){  // wave 0: geometry, run table, gauss cols
      float* q_rel  = (float*)(tq);
      float* q_dist = (float*)(tq+192);
      float* q_pe   = (float*)(tq+256);
      float* q_pg   = (float*)(tq+320);
      int*   q_udst = (int*)(tq+384);
      int*   q_ust  = (int*)(tq+448);
      int*   q_slot = (int*)(tq+514);
      const uint32_t* ed = edata + (size_t)(nb + tid)*EDW;
      const u32x4 w0 = *reinterpret_cast<const u32x4*>(ed);
      const u32x4 w1 = *reinterpret_cast<const u32x4*>(ed + 4);
      const u32x4 w2 = *reinterpret_cast<const u32x4*>(ed + 8);
      const int dj   = (int)w0.y;
      const float ax = __uint_as_float(w0.z);
      const float ay = __uint_as_float(w0.w);
      const float az = __uint_as_float(w1.x);
      const float dd = __uint_as_float(w1.y);
      q_rel[3*tid+0]=ax; q_rel[3*tid+1]=ay; q_rel[3*tid+2]=az;
      q_dist[tid]=dd; q_pe[tid]=0.0f; q_pg[tid]=0.0f;
      const int dprev = __shfl_up(dj, 1);
      const int isnew = (tid == 0) || (dj != dprev);
      const unsigned long long mball = __ballot(isnew);
      const int slot = __popcll(mball << (63 - tid)) - 1;
      q_slot[tid] = slot;
      if (isnew){ q_udst[slot] = dj; q_ust[slot] = tid; }
      if (tid == 63){ q_ust[slot + 1] = 64; q_ust[65] = slot + 1; }
      float g[24];
      #pragma unroll
      for (int j = 0; j < 20; ++j){ const float a = dd - j*SP; g[j] = __expf(CO*a*a); }
      g[20]=__uint_as_float(w1.z); g[21]=__uint_as_float(w1.w);
      g[22]=__uint_as_float(w2.x); g[23]=__uint_as_float(w2.y);
      uint32_t* gp = s_inp + tid*ROWU + 128;
      u32x4 g0v = {pk2(g[0],g[1]),  pk2(g[2],g[3]),  pk2(g[4],g[5]),  pk2(g[6],g[7])};
      u32x4 g1v = {pk2(g[8],g[9]),  pk2(g[10],g[11]),pk2(g[12],g[13]),pk2(g[14],g[15])};
      u32x4 g2v = {pk2(g[16],g[17]),pk2(g[18],g[19]),pk2(g[20],g[21]),pk2(g[22],g[23])};
      u32x4 g3v = {0,0,0,0};
      *reinterpret_cast<u32x4*>(gp)    = g0v;
      *reinterpret_cast<u32x4*>(gp+4)  = g1v;
      *reinterpret_cast<u32x4*>(gp+8)  = g2v;
      *reinterpret_cast<u32x4*>(gp+12) = g3v;
    }
  };

  // prologue: stage first tile
  stage(blockIdx.x*64, tlb);
  __syncthreads();

  int p = 0;
  for (int t = blockIdx.x; t < TILES; t += EGRID, p ^= 1){
    uint32_t* tlp = tlb + p*TLW;
    float* s_rel  = (float*)(tlp);
    float* s_dist = (float*)(tlp+192);
    float* s_pe   = (float*)(tlp+256);
    float* s_pg   = (float*)(tlp+320);
    int*   s_udst = (int*)(tlp+384);
    int*   s_ust  = (int*)(tlp+448);
    int*   s_slot = (int*)(tlp+514);

    // ---------------- GEMM1: t1 = silu(inp @ We1 + be1) ----------------
    #pragma unroll
    for (int Mt = 0; Mt < 4; ++Mt){
      const uint32_t* arow = s_inp + (Mt*16 + lo)*ROWU + hi*4;
      f32x4 acc = {0,0,0,0};
      #pragma unroll
      for (int ks = 0; ks < 9; ++ks)
        acc = MF(*reinterpret_cast<const u32x4*>(arow + ks*16), B1[ks], acc);
      #pragma unroll
      for (int reg = 0; reg < 4; ++reg)
        t1f[((Mt*4 + ks2)*64 + SW(lp+reg))*8 + jj] = bfb(silu_f(acc[reg] + vbe1));
    }
    __syncthreads();               // A: t1f ready, s_inp(t) dead

    // ---- stage tile t+1 (overlaps GEMM2/scatter/GEMM3 via TLP) ----
    if (t + EGRID < TILES) stage((t + EGRID)*64, tlb + (p^1)*TLW);

    // ---------------- GEMM2: mij = silu(t1 @ We2 + be2); eij partials ----
    #pragma unroll
    for (int Mt = 0; Mt < 4; ++Mt){
      f32x4 acc = {0,0,0,0};
      #pragma unroll
      for (int ks = 0; ks < 4; ++ks)
        acc = MF(*reinterpret_cast<const u32x4*>(t1f + ((Mt*4+ks)*64 + lsw)*8), B2[ks], acc);
      float pq[4];
      #pragma unroll
      for (int reg = 0; reg < 4; ++reg){
        const float m = silu_f(acc[reg] + vbe2);
        mf_[((Mt*4 + ks2)*64 + SW(lp+reg))*8 + jj] = bfb(m);
        pq[reg] = m * wi;
      }
      #pragma unroll
      for (int msk = 1; msk < 16; msk <<= 1){
        #pragma unroll
        for (int reg = 0; reg < 4; ++reg) pq[reg] += __shfl_xor(pq[reg], msk);
      }
      if (lo == 0){
        #pragma unroll
        for (int reg = 0; reg < 4; ++reg) atomicAdd(&s_pe[Mt*16 + 4*hi + reg], pq[reg]);
      }
    }
    __syncthreads();               // B: mf_ + s_pe ready

    // ---- per-wave redundant eij precompute (no barrier needed) ----
    s_eij[l] = sigmoid_f(s_pe[l] + vbinf);

    // ---- mi scatter: balanced run-flush, thread owns (row-group, col) ----
    {
      const int rb16 = (tid >> 7) << 4;             // 0,16,32,48
      const int c    = tid & 127;
      const int cb = c >> 5, cc = ((c>>4)&1)*2 + ((c>>3)&1);
      const int base = (rb16 >> 4)*2048 + (cb*64 + cc*16)*8 + (c & 7);
      const int x2 = cc*2;
      float acc = 0.0f;
      int sprev = s_slot[rb16];
      #pragma unroll
      for (int i = 0; i < 16; ++i){
        const int s = s_slot[rb16 + i];
        if (s != sprev){                            // wave-uniform branch
          atomicAdd(out + (size_t)s_udst[sprev]*HD + c, acc);
          acc = 0.0f; sprev = s;
        }
        const int mix = base + ((i ^ ((x2 + (i>>3))&7)) << 3);
        acc += bf2f(mf_[mix]) * s_eij[rb16 + i];
      }
      atomicAdd(out + (size_t)s_udst[sprev]*HD + c, acc);
    }
    // ---------------- GEMM3: gate partials (hides atomic latency) --------
    #pragma unroll
    for (int Mt = 0; Mt < 4; ++Mt){
      f32x4 acc = {0,0,0,0};
      #pragma unroll
      for (int ks = 0; ks < 4; ++ks)
        acc = MF(*reinterpret_cast<const u32x4*>(mf_ + ((Mt*4+ks)*64 + lsw)*8), B3[ks], acc);
      float pq[4];
      #pragma unroll
      for (int reg = 0; reg < 4; ++reg)
        pq[reg] = silu_f(acc[reg] + vbx1) * wx;
      #pragma unroll
      for (int msk = 1; msk < 16; msk <<= 1){
        #pragma unroll
        for (int reg = 0; reg < 4; ++reg) pq[reg] += __shfl_xor(pq[reg], msk);
      }
      if (lo == 0){
        #pragma unroll
        for (int reg = 0; reg < 4; ++reg) atomicAdd(&s_pg[Mt*16 + 4*hi + reg], pq[reg]);
      }
    }
    __syncthreads();               // D: s_pg ready; stage(t+1) writes visible

    // ---- dx run-reduced scatter (wave 0 only) ----
    if (tid < 64){
      const int U = s_ust[65];
      s_eij[tid] = tanh_f(s_pg[tid]) * fast_rcp(s_dist[tid] + 1.0f);
      for (int idx = tid; idx < U*3; idx += 64){
        const int u = idx/3, cc2 = idx - 3*u;
        float acc = 0.0f;
        for (int r = s_ust[u]; r < s_ust[u+1]; ++r)
          acc += s_rel[3*r+cc2] * s_eij[r];
        atomicAdd(out + (size_t)NN*HD + (size_t)s_udst[u]*3 + cc2, acc);
      }
    }
    // no loop-top barrier (see R12 ordering argument; verified passing)
  }
}

// ---------------------------------------------------------------------------
// Fallback edge kernel (round 6, f32-h, unsorted per-edge atomics).
// ---------------------------------------------------------------------------
#define FB_LDS_U32 (64*ROWU + 4096 + 4096 + 448)
#define FB_LDS_B (FB_LDS_U32*4)

__global__ void __launch_bounds__(512, 4) edge_fb_kernel(
    const float* __restrict__ h, const float* __restrict__ x,
    const int* __restrict__ ei, const float* __restrict__ eattr,
    const float* __restrict__ We1, const float* __restrict__ be1,
    const float* __restrict__ We2, const float* __restrict__ be2,
    const float* __restrict__ Winf, const float* __restrict__ binf,
    const float* __restrict__ Wx1, const float* __restrict__ bx1,
    const float* __restrict__ Wx2, float* __restrict__ out)
{
  extern __shared__ uint32_t smem[];
  uint32_t* s_inp = smem;
  uint16_t* t1f   = (uint16_t*)(smem + 64*ROWU);
  uint16_t* mf_   = (uint16_t*)(smem + 64*ROWU + 4096);
  uint32_t* tl    = smem + 64*ROWU + 8192;
  int*   s_dst  = (int*)tl;
  float* s_rel  = (float*)(tl+64);
  float* s_dist = (float*)(tl+256);
  float* s_pe   = (float*)(tl+320);
  float* s_pg   = (float*)(tl+384);

  const int tid = threadIdx.x;
  const int w = tid >> 6, l = tid & 63;
  const int lo = l & 15, hi = l >> 4;
  const int col = w*16 + lo;
  const int r8 = tid >> 3, p8 = tid & 7;
  const int ks2 = w >> 1;
  const int lp  = ((w&1)*2 + (lo>>3))*16 + 4*hi;
  const int jj  = lo & 7;
  const int lsw = SW(l);

  u32x4 B1[9], B2[4], B3[4];
  #pragma unroll
  for (int ks = 0; ks < 9; ++ks){
    float f[8];
    #pragma unroll
    for (int j = 0; j < 8; ++j){
      const int k = ks*32 + hi*8 + j;
      f[j] = (k < K1) ? We1[k*HD + col] : 0.0f;
    }
    B1[ks] = {pk2(f[0],f[1]), pk2(f[2],f[3]), pk2(f[4],f[5]), pk2(f[6],f[7])};
  }
  #pragma unroll
  for (int ks = 0; ks < 4; ++ks){
    float f2[8], f3[8];
    #pragma unroll
    for (int j = 0; j < 8; ++j){
      const int k = ks*32 + hi*8 + j;
      f2[j] = We2[k*HD + col];
      f3[j] = Wx1[k*HD + col];
    }
    B2[ks] = {pk2(f2[0],f2[1]), pk2(f2[2],f2[3]), pk2(f2[4],f2[5]), pk2(f2[6],f2[7])};
    B3[ks] = {pk2(f3[0],f3[1]), pk2(f3[2],f3[3]), pk2(f3[4],f3[5]), pk2(f3[6],f3[7])};
  }
  const float vbe1 = be1[col], vbe2 = be2[col], vbx1 = bx1[col];
  const float wi = Winf[col], wx = Wx2[col], vbinf = binf[0];
  const float SP = 10.0f/19.0f;
  const float CO = -0.5f/(SP*SP);

  for (int t = blockIdx.x; t < TILES; t += EGRID){
    const int ebase = t*64;
    __syncthreads();
    if (tid < 64){
      const int sj = ei[ebase+tid], dj = ei[NE+ebase+tid];
      const float ax = x[dj*3+0]-x[sj*3+0];
      const float ay = x[dj*3+1]-x[sj*3+1];
      const float az = x[dj*3+2]-x[sj*3+2];
      const float dd = sqrtf(ax*ax + ay*ay + az*az + 1e-8f);
      s_dst[tid] = dj;
      s_rel[3*tid+0]=ax; s_rel[3*tid+1]=ay; s_rel[3*tid+2]=az;
      s_dist[tid]=dd; s_pe[tid]=0.0f; s_pg[tid]=0.0f;
      float g[24];
      #pragma unroll
      for (int j = 0; j < 20; ++j){ const float a = dd - j*SP; g[j] = __expf(CO*a*a); }
      const float4 e4 = *reinterpret_cast<const float4*>(eattr + (size_t)(ebase+tid)*EF);
      g[20]=e4.x; g[21]=e4.y; g[22]=e4.z; g[23]=e4.w;
      uint32_t* gp = s_inp + tid*ROWU + 128;
      u32x4 g0v = {pk2(g[0],g[1]),  pk2(g[2],g[3]),  pk2(g[4],g[5]),  pk2(g[6],g[7])};
      u32x4 g1v = {pk2(g[8],g[9]),  pk2(g[10],g[11]),pk2(g[12],g[13]),pk2(g[14],g[15])};
      u32x4 g2v = {pk2(g[16],g[17]),pk2(g[18],g[19]),pk2(g[20],g[21]),pk2(g[22],g[23])};
      u32x4 g3v = {0,0,0,0};
      *reinterpret_cast<u32x4*>(gp)    = g0v;
      *reinterpret_cast<u32x4*>(gp+4)  = g1v;
      *reinterpret_cast<u32x4*>(gp+8)  = g2v;
      *reinterpret_cast<u32x4*>(gp+12) = g3v;
    }
    {
      const int e = ebase + r8;
      const int node = (p8 < 4) ? ei[NE + e] : ei[e];
      const float* hp = h + (size_t)node*HD + (p8&3)*32;
      uint32_t* dp = s_inp + r8*ROWU + p8*16;
      #pragma unroll
      for (int q = 0; q < 4; ++q){
        const float4 va = *reinterpret_cast<const float4*>(hp + 8*q);
        const float4 vb = *reinterpret_cast<const float4*>(hp + 8*q + 4);
        u32x4 v = { pk2(va.x,va.y), pk2(va.z,va.w), pk2(vb.x,vb.y), pk2(vb.z,vb.w) };
        *reinterpret_cast<u32x4*>(dp + 4*q) = v;
      }
    }
    __syncthreads();

    #pragma unroll
    for (int Mt = 0; Mt < 4; ++Mt){
      const uint32_t* arow = s_inp + (Mt*16 + lo)*ROWU + hi*4;
      f32x4 acc = {0,0,0,0};
      #pragma unroll
      for (int ks = 0; ks < 9; ++ks)
        acc = MF(*reinterpret_cast<const u32x4*>(arow + ks*16), B1[ks], acc);
      #pragma unroll
      for (int reg = 0; reg < 4; ++reg)
        t1f[((Mt*4 + ks2)*64 + SW(lp+reg))*8 + jj] = bfb(silu_f(acc[reg] + vbe1));
    }
    __syncthreads();

    #pragma unroll
    for (int Mt = 0; Mt < 4; ++Mt){
      f32x4 acc = {0,0,0,0};
      #pragma unroll
      for (int ks = 0; ks < 4; ++ks)
        acc = MF(*reinterpret_cast<const u32x4*>(t1f + ((Mt*4+ks)*64 + lsw)*8), B2[ks], acc);
      float pq[4];
      #pragma unroll
      for (int reg = 0; reg < 4; ++reg){
        const float m = silu_f(acc[reg] + vbe2);
        mf_[((Mt*4 + ks2)*64 + SW(lp+reg))*8 + jj] = bfb(m);
        pq[reg] = m * wi;
      }
      #pragma unroll
      for (int msk = 1; msk < 16; msk <<= 1){
        #pragma unroll
        for (int reg = 0; reg < 4; ++reg) pq[reg] += __shfl_xor(pq[reg], msk);
      }
      if (lo == 0){
        #pragma unroll
        for (int reg = 0; reg < 4; ++reg) atomicAdd(&s_pe[Mt*16 + 4*hi + reg], pq[reg]);
      }
    }
    __syncthreads();

    #pragma unroll
    for (int Mt = 0; Mt < 4; ++Mt){
      #pragma unroll
      for (int reg = 0; reg < 4; ++reg){
        const int r = Mt*16 + 4*hi + reg;
        const float eij = sigmoid_f(s_pe[r] + vbinf);
        const float m = bf2f(mf_[((Mt*4 + ks2)*64 + SW(lp+reg))*8 + jj]);
        atomicAdd(out + (size_t)s_dst[r]*HD + col, m*eij);
      }
    }
    #pragma unroll
    for (int Mt = 0; Mt < 4; ++Mt){
      f32x4 acc = {0,0,0,0};
      #pragma unroll
      for (int ks = 0; ks < 4; ++ks)
        acc = MF(*reinterpret_cast<const u32x4*>(mf_ + ((Mt*4+ks)*64 + lsw)*8), B3[ks], acc);
      float pq[4];
      #pragma unroll
      for (int reg = 0; reg < 4; ++reg)
        pq[reg] = silu_f(acc[reg] + vbx1) * wx;
      #pragma unroll
      for (int msk = 1; msk < 16; msk <<= 1){
        #pragma unroll
        for (int reg = 0; reg < 4; ++reg) pq[reg] += __shfl_xor(pq[reg], msk);
      }
      if (lo == 0){
        #pragma unroll
        for (int reg = 0; reg < 4; ++reg) atomicAdd(&s_pg[Mt*16 + 4*hi + reg], pq[reg]);
      }
    }
    __syncthreads();

    if (tid < 192){
      const int er = tid/3, c = tid - 3*er;
      const float gate = tanh_f(s_pg[er]);
      const float sc = gate * fast_rcp(s_dist[er] + 1.0f);
      atomicAdd(out + (size_t)NN*HD + (size_t)s_dst[er]*3 + c, s_rel[3*er+c]*sc);
    }
  }
}

// ---------------------------------------------------------------------------
// Node kernel (MFMA), unchanged.
// ---------------------------------------------------------------------------
#define CROW 132

__global__ void __launch_bounds__(512, 4) node_kernel(
    const float* __restrict__ h, const float* __restrict__ x,
    const float* __restrict__ mask,
    const float* __restrict__ Wn1, const float* __restrict__ bn1,
    const float* __restrict__ Wn2, const float* __restrict__ bn2,
    float* __restrict__ out)
{
  __shared__ uint32_t s_cat[64*CROW];
  __shared__ __align__(16) uint16_t t1n[4*4*64*8];

  const int tid = threadIdx.x;
  const int w = tid >> 6, l = tid & 63;
  const int lo = l & 15, hi = l >> 4;
  const int col = w*16 + lo;

  u32x4 Bn1[8], Bn2[4];
  #pragma unroll
  for (int ks = 0; ks < 8; ++ks){
    float f[8];
    #pragma unroll
    for (int j = 0; j < 8; ++j) f[j] = Wn1[(ks*32 + hi*8 + j)*HD + col];
    Bn1[ks] = {pk2(f[0],f[1]), pk2(f[2],f[3]), pk2(f[4],f[5]), pk2(f[6],f[7])};
  }
  #pragma unroll
  for (int ks = 0; ks < 4; ++ks){
    float f[8];
    #pragma unroll
    for (int j = 0; j < 8; ++j) f[j] = Wn2[(ks*32 + hi*8 + j)*HD + col];
    Bn2[ks] = {pk2(f[0],f[1]), pk2(f[2],f[3]), pk2(f[4],f[5]), pk2(f[6],f[7])};
  }
  const float vbn1 = bn1[col], vbn2 = bn2[col];
  const int nbase = blockIdx.x*64;
  const int ks2 = w >> 1;
  const int lp  = ((w&1)*2 + (lo>>3))*16 + 4*hi;
  const int jj  = lo & 7;

  {
    const int r = tid >> 3, pp = tid & 7;
    const int n = nbase + r;
    uint32_t* dp = s_cat + r*CROW + pp*16;
    if (n < NN){
      const float* sp = (pp < 4) ? (out + (size_t)n*HD + pp*32)
                                 : (h   + (size_t)n*HD + (pp-4)*32);
      #pragma unroll
      for (int q = 0; q < 8; ++q){
        const float4 v = *reinterpret_cast<const float4*>(sp + 4*q);
        dp[2*q]   = pk2(v.x, v.y);
        dp[2*q+1] = pk2(v.z, v.w);
      }
    } else {
      #pragma unroll
      for (int q = 0; q < 16; ++q) dp[q] = 0u;
    }
  }
  __syncthreads();

  #pragma unroll
  for (int Mt = 0; Mt < 4; ++Mt){
    const uint32_t* arow = s_cat + (Mt*16 + lo)*CROW + hi*4;
    f32x4 acc = {0,0,0,0};
    #pragma unroll
    for (int ks = 0; ks < 8; ++ks)
      acc = MF(*reinterpret_cast<const u32x4*>(arow + ks*16), Bn1[ks], acc);
    uint16_t* tp = t1n + ((Mt*4 + ks2)*64 + lp)*8 + jj;
    #pragma unroll
    for (int reg = 0; reg < 4; ++reg)
      tp[reg*8] = bfb(silu_f(acc[reg] + vbn1));
  }
  __syncthreads();

  #pragma unroll
  for (int Mt = 0; Mt < 4; ++Mt){
    f32x4 acc = {0,0,0,0};
    #pragma unroll
    for (int ks = 0; ks < 4; ++ks)
      acc = MF(*reinterpret_cast<const u32x4*>(t1n + ((Mt*4+ks)*64 + l)*8), Bn2[ks], acc);
    #pragma unroll
    for (int reg = 0; reg < 4; ++reg){
      const int n = nbase + Mt*16 + 4*hi + reg;
      if (n < NN)
        out[(size_t)n*HD + col] = h[(size_t)n*HD + col] + acc[reg] + vbn2;
    }
  }

  if (tid < 192){
    const int r = tid/3, c = tid - 3*r;
    const int n = nbase + r;
    if (n < NN){
      const size_t ix = (size_t)NN*HD + (size_t)n*3 + c;
      out[ix] = x[(size_t)n*3 + c] + out[ix]*mask[n];
    }
  }
}

extern "C" void kernel_launch(void* const* d_in, const int* in_sizes, int n_in,
                              void* d_out, int out_size, void* d_ws, size_t ws_size,
                              hipStream_t stream) {
  (void)in_sizes; (void)n_in;
  const float* h    = (const float*)d_in[0];
  const float* x    = (const float*)d_in[1];
  const int*   ei   = (const int*)  d_in[2];
  const float* mask = (const float*)d_in[3];
  const float* ea   = (const float*)d_in[4];
  const float* We1  = (const float*)d_in[5];
  const float* be1  = (const float*)d_in[6];
  const float* We2  = (const float*)d_in[7];
  const float* be2  = (const float*)d_in[8];
  const float* Winf = (const float*)d_in[9];
  const float* binf = (const float*)d_in[10];
  const float* Wx1  = (const float*)d_in[11];
  const float* bx1  = (const float*)d_in[12];
  const float* Wx2  = (const float*)d_in[13];
  const float* Wn1  = (const float*)d_in[14];
  const float* bn1  = (const float*)d_in[15];
  const float* Wn2  = (const float*)d_in[16];
  const float* bn2  = (const float*)d_in[17];
  float* out = (float*)d_out;

  // ws layout (u32): hb[3.2M] | cursor[50k] | bsums[128] | edata[7.2M]
  uint32_t* hb    = (uint32_t*)d_ws;
  int* cursor     = (int*)d_ws + 3200000;
  int* bsums      = (int*)d_ws + 3250000;
  uint32_t* edata = (uint32_t*)d_ws + 3250128;
  const size_t need = (size_t)(3250128 + (size_t)NE*EDW) * 4;   // ~41.8 MB
  const bool use_red = ws_size >= need;

  hipFuncSetAttribute(reinterpret_cast<const void*>(edge_red_kernel),
                      hipFuncAttributeMaxDynamicSharedMemorySize, EDGE_LDS_B);
  hipFuncSetAttribute(reinterpret_cast<const void*>(edge_fb_kernel),
                      hipFuncAttributeMaxDynamicSharedMemorySize, FB_LDS_B);

  // out[0..NN*HD) accumulates mi; out[NN*HD..) accumulates delta_x
  hipMemsetAsync(d_out, 0, (size_t)out_size * sizeof(float), stream);

  if (use_red){
    hipMemsetAsync(cursor, 0, (size_t)NN*4, stream);
    h2bf_hist_kernel<<<1563, 512, 0, stream>>>(h, hb, ei, cursor);
    scanA_kernel<<<98, 512, 0, stream>>>(cursor, bsums);
    scanBC_kernel<<<98, 512, 0, stream>>>(cursor, bsums);
    fillpg_kernel<<<2344, 256, 0, stream>>>(ei, x, ea, cursor, edata);
    edge_red_kernel<<<EGRID, 512, EDGE_LDS_B, stream>>>(
        hb, edata, We1, be1, We2, be2, Winf, binf, Wx1, bx1, Wx2, out);
  } else {
    edge_fb_kernel<<<EGRID, 512, FB_LDS_B, stream>>>(
        h, x, ei, ea, We1, be1, We2, be2, Winf, binf, Wx1, bx1, Wx2, out);
  }
  node_kernel<<<NTILE, 512, 0, stream>>>(
      h, x, mask, Wn1, bn1, Wn2, bn2, out);
}